// Round 10
// baseline (86.479 us; speedup 1.0000x reference)
//
#include <hip/hip_runtime.h>
#include <hip/hip_bf16.h>

// MoE forward, top-2 sparse gather-GEMM.
// T=2048, D=512, F=1024, E=8, top-2. fp32 in/out, bf16 MFMA internally.
//
// Round 10: fuse fp32->bf16 weight conversion INTO the GEMM B-staging.
//  - no transposed weight intermediates: gemm1 reads w1/w3 native [E][D][F],
//    gemm2 reads w2 native [E][F][D]; reg-stage + pack bf16x2 along k-pairs
//    -> ds_write_b32 into the XOR-swizzled [n][k] LDS tile (transpose falls
//    out of the packing; write ops conflict-free across lanes)
//  - T14 pipeline: {loadB(t+1)->regs, gload_lds A(t+1)} ; COMPUTE(t) ;
//    vmcnt(0) ; convert+write B(t+1) ; lgkmcnt(0)+barrier  (ONE barrier/step)
//  - prep: router + x->bf16 + pair/sched init only (520 blocks)
//  - build: R6 simple-atomic (ballot variant regressed; R9 confirmed)

typedef __attribute__((ext_vector_type(4))) float f32x4;
typedef __attribute__((ext_vector_type(8))) __bf16 bf16x8;
typedef __attribute__((ext_vector_type(2))) __bf16 bf16x2;

#define T_TOK 2048
#define DMODEL 512
#define FFN 1024
#define NE 8
#define MAXMB 40
#define PCAP (MAXMB * 128)

__device__ __forceinline__ void gload_lds16(const void* g, void* l) {
  __builtin_amdgcn_global_load_lds(
      (const __attribute__((address_space(1))) void*)g,
      (__attribute__((address_space(3))) void*)l, 16, 0, 0);
}

#define VM0()                                               \
  asm volatile("s_waitcnt vmcnt(0)" ::: "memory");          \
  __builtin_amdgcn_sched_barrier(0)
#define LG0_BAR()                                           \
  asm volatile("s_waitcnt lgkmcnt(0)" ::: "memory");        \
  __builtin_amdgcn_s_barrier();                             \
  __builtin_amdgcn_sched_barrier(0)

// ---------------- prep: cvt_router + inits ----------------
__global__ __launch_bounds__(256) void prep_kernel(
    const float* __restrict__ x, const float* __restrict__ rw,
    __bf16* __restrict__ xb, int* __restrict__ tope, float* __restrict__ topw,
    int* __restrict__ pair_t, float* __restrict__ pair_w,
    int* __restrict__ sched_e) {
  const int bx = blockIdx.x;
  const int tid = threadIdx.x;
  if (bx < 512) {
    // ---- x -> bf16 + router top-2 ----
    const int t = bx * 4 + (tid >> 6);
    const int lane = tid & 63;
    const float* xr = x + (size_t)t * DMODEL + lane * 8;
    const f32x4 a = *(const f32x4*)xr;
    const f32x4 b = *(const f32x4*)(xr + 4);
    bf16x8 v;
    v[0] = (__bf16)a[0]; v[1] = (__bf16)a[1]; v[2] = (__bf16)a[2]; v[3] = (__bf16)a[3];
    v[4] = (__bf16)b[0]; v[5] = (__bf16)b[1]; v[6] = (__bf16)b[2]; v[7] = (__bf16)b[3];
    *(bf16x8*)&xb[(size_t)t * DMODEL + lane * 8] = v;

    float xv[8] = {a[0], a[1], a[2], a[3], b[0], b[1], b[2], b[3]};
    float part[NE];
#pragma unroll
    for (int e = 0; e < NE; ++e) part[e] = 0.f;
#pragma unroll
    for (int i = 0; i < 8; ++i) {
      const int d = lane * 8 + i;
      const f32x4 r0 = *(const f32x4*)&rw[(size_t)d * NE];
      const f32x4 r1 = *(const f32x4*)&rw[(size_t)d * NE + 4];
      part[0] += xv[i] * r0[0]; part[1] += xv[i] * r0[1];
      part[2] += xv[i] * r0[2]; part[3] += xv[i] * r0[3];
      part[4] += xv[i] * r1[0]; part[5] += xv[i] * r1[1];
      part[6] += xv[i] * r1[2]; part[7] += xv[i] * r1[3];
    }
#pragma unroll
    for (int off = 32; off > 0; off >>= 1) {
#pragma unroll
      for (int e = 0; e < NE; ++e) part[e] += __shfl_xor(part[e], off);
    }
    if (lane == 0) {
      int ia = 0;
#pragma unroll
      for (int e = 1; e < NE; ++e)
        if (part[e] > part[ia]) ia = e;
      int ib = (ia == 0) ? 1 : 0;
#pragma unroll
      for (int e = 0; e < NE; ++e)
        if (e != ia && e != ib && part[e] > part[ib]) ib = e;
      const float wa = 1.f / (1.f + __expf(part[ib] - part[ia]));
      tope[t * 2] = ia;
      tope[t * 2 + 1] = ib;
      topw[t * 2] = wa;
      topw[t * 2 + 1] = 1.f - wa;
    }
  } else {
    // ---- init pair lists (padding rows = token 0, weight 0) + schedule ----
    const int i = (bx - 512) * 256 + tid;  // 0..2047
    for (int j = i; j < PCAP; j += 2048) { pair_t[j] = 0; pair_w[j] = 0.f; }
    if (i < MAXMB) sched_e[i] = -1;
  }
}

// ---------------- build: count + schedule + scatter (simple-atomic) ----------------
__global__ __launch_bounds__(256) void build_kernel(
    const int* __restrict__ tope, const float* __restrict__ topw,
    int* __restrict__ pair_t, float* __restrict__ pair_w,
    int* __restrict__ pairidx, int* __restrict__ sched_e) {
  __shared__ int cnt[NE], base[NE], ofs[NE];
  const int tid = threadIdx.x;
  if (tid < NE) { cnt[tid] = 0; ofs[tid] = 0; }
  __syncthreads();
  for (int t = tid; t < T_TOK; t += 256) {
    atomicAdd(&cnt[tope[t * 2]], 1);
    atomicAdd(&cnt[tope[t * 2 + 1]], 1);
  }
  __syncthreads();
  if (tid == 0) {
    int mb = 0;
    for (int e = 0; e < NE; ++e) {
      base[e] = mb * 128;
      const int nmb = (cnt[e] + 127) >> 7;
      for (int i = 0; i < nmb; ++i) sched_e[mb + i] = e;
      mb += nmb;
    }
  }
  __syncthreads();
  for (int t = tid; t < T_TOK; t += 256) {
#pragma unroll
    for (int s = 0; s < 2; ++s) {
      const int e = tope[t * 2 + s];
      const int pos = base[e] + atomicAdd(&ofs[e], 1);
      pair_t[pos] = t;
      pair_w[pos] = topw[t * 2 + s];
      pairidx[t * 2 + s] = pos;
    }
  }
}

// ---------------- GEMM1 sparse: 128(pairs) x 64(f), BK=64, fused-convert B ----------------
// A: xb bf16 gathered via gload_lds (inverse-swizzled source).
// B: w1/w3 fp32 native [E][D][F]; thread (dp=tid&31, fq=tid>>5) loads d-pair
// rows {2dp,2dp+1} x 8 f-values, packs bf16x2 along d, writes [f][d] tile
// swizzled: byte (fq*8+fi)*128 + (dp*4 ^ (fi<<4)).
__global__ __launch_bounds__(256) void gemm1_kernel(
    const __bf16* __restrict__ xb, const float* __restrict__ w1,
    const float* __restrict__ w3, const int* __restrict__ pair_t,
    const float* __restrict__ pair_w, const int* __restrict__ sched_e,
    __bf16* __restrict__ hbuf) {
  __shared__ alignas(16) __bf16 As[2][128 * 64];
  __shared__ alignas(16) __bf16 B1s[2][64 * 64];
  __shared__ alignas(16) __bf16 B3s[2][64 * 64];
  __shared__ float comb[128];
  const int tid = threadIdx.x;
  const int id = blockIdx.x;
  const int mb = (id & 7) + ((id >> 7) << 3);
  const int f0 = ((id >> 3) & 15) * 64;
  const int e = sched_e[mb];
  if (e < 0) return;
  const int m0 = mb * 128;
  const int lane = tid & 63;
  const int wv = tid >> 6;
  const int wr = wv >> 1, wc = wv & 1;
  const int l15 = lane & 15, lhi = lane >> 4;
  const int sw = (l15 & 7) << 4;
  const int dp = tid & 31, fq = tid >> 5;

  if (tid < 128) comb[tid] = pair_w[m0 + tid];

  size_t aoff[4];
  int lbA[4];
#pragma unroll
  for (int it = 0; it < 4; ++it) {
    const int chunk = it * 256 + tid;
    const int r = chunk >> 3;
    const int c8 = ((chunk & 7) ^ (r & 7)) * 8;
    aoff[it] = (size_t)pair_t[m0 + r] * DMODEL + c8;
    lbA[it] = (it * 256 + (tid & ~63)) * 16;
  }
  // B source base: row d = k0 + 2*dp, cols f0 + fq*8 .. +8
  const float* b1base = w1 + ((size_t)e * DMODEL + 2 * dp) * FFN + f0 + fq * 8;
  const float* b3base = w3 + ((size_t)e * DMODEL + 2 * dp) * FFN + f0 + fq * 8;

  const f32x4 fz = {0.f, 0.f, 0.f, 0.f};
  f32x4 acc1[4][2], acc3[4][2];
#pragma unroll
  for (int m = 0; m < 4; ++m)
#pragma unroll
    for (int n = 0; n < 2; ++n) { acc1[m][n] = fz; acc3[m][n] = fz; }

  f32x4 q1[4], q3[4];

#define G1_LOADB(K0)                                                          \
  do {                                                                        \
    const float* p1 = b1base + (size_t)(K0)*FFN;                              \
    const float* p3 = b3base + (size_t)(K0)*FFN;                              \
    q1[0] = *(const f32x4*)p1;        q1[1] = *(const f32x4*)(p1 + 4);        \
    q1[2] = *(const f32x4*)(p1 + FFN); q1[3] = *(const f32x4*)(p1 + FFN + 4); \
    q3[0] = *(const f32x4*)p3;        q3[1] = *(const f32x4*)(p3 + 4);        \
    q3[2] = *(const f32x4*)(p3 + FFN); q3[3] = *(const f32x4*)(p3 + FFN + 4); \
  } while (0)

#define G1_STAGEA(BUF, K0)                                                    \
  do {                                                                        \
    _Pragma("unroll") for (int it = 0; it < 4; ++it)                          \
        gload_lds16(xb + aoff[it] + (K0), (char*)As[BUF] + lbA[it]);          \
  } while (0)

#define G1_WRITEB(BUF)                                                        \
  do {                                                                        \
    _Pragma("unroll") for (int fi = 0; fi < 8; ++fi) {                        \
      const float l1 = fi < 4 ? q1[0][fi] : q1[1][fi - 4];                    \
      const float h1 = fi < 4 ? q1[2][fi] : q1[3][fi - 4];                    \
      const float l3 = fi < 4 ? q3[0][fi] : q3[1][fi - 4];                    \
      const float h3 = fi < 4 ? q3[2][fi] : q3[3][fi - 4];                    \
      const int ad = (fq * 8 + fi) * 128 + ((dp * 4) ^ (fi << 4));            \
      bf16x2 v1 = {(__bf16)l1, (__bf16)h1};                                   \
      bf16x2 v3 = {(__bf16)l3, (__bf16)h3};                                   \
      *(bf16x2*)((char*)B1s[BUF] + ad) = v1;                                  \
      *(bf16x2*)((char*)B3s[BUF] + ad) = v3;                                  \
    }                                                                         \
  } while (0)

#define G1_COMPUTE(BUF)                                                       \
  do {                                                                        \
    __builtin_amdgcn_s_setprio(1);                                            \
    _Pragma("unroll") for (int kk = 0; kk < 2; ++kk) {                        \
      const int ko = (kk * 64 + lhi * 16) ^ sw;                               \
      bf16x8 af[4], b1f[2], b3f[2];                                           \
      _Pragma("unroll") for (int m = 0; m < 4; ++m)                           \
          af[m] = *(const bf16x8*)((const char*)As[BUF] +                     \
                                   (wr * 64 + m * 16 + l15) * 128 + ko);      \
      _Pragma("unroll") for (int n = 0; n < 2; ++n) {                         \
        const int ro = (wc * 32 + n * 16 + l15) * 128 + ko;                   \
        b1f[n] = *(const bf16x8*)((const char*)B1s[BUF] + ro);                \
        b3f[n] = *(const bf16x8*)((const char*)B3s[BUF] + ro);                \
      }                                                                       \
      _Pragma("unroll") for (int m = 0; m < 4; ++m)                           \
          _Pragma("unroll") for (int n = 0; n < 2; ++n) {                     \
        acc1[m][n] = __builtin_amdgcn_mfma_f32_16x16x32_bf16(af[m], b1f[n],   \
                                                             acc1[m][n], 0, 0, 0); \
        acc3[m][n] = __builtin_amdgcn_mfma_f32_16x16x32_bf16(af[m], b3f[n],   \
                                                             acc3[m][n], 0, 0, 0); \
      }                                                                       \
    }                                                                         \
    __builtin_amdgcn_s_setprio(0);                                            \
  } while (0)

  // prologue: fill buffer 0
  G1_LOADB(0);
  G1_STAGEA(0, 0);
  VM0();
  G1_WRITEB(0);
  LG0_BAR();
  // main loop: one barrier per K-step
#pragma unroll
  for (int t = 0; t < 7; ++t) {
    G1_LOADB((t + 1) * 64);
    G1_STAGEA((t + 1) & 1, (t + 1) * 64);
    G1_COMPUTE(t & 1);
    VM0();
    G1_WRITEB((t + 1) & 1);
    LG0_BAR();
  }
  G1_COMPUTE(1);

  // ---- LDS-bounce epilogue: silu(g)*u*w -> pad-72 scratch -> coalesced b128 ----
  __syncthreads();
  {
    __bf16* eps = (__bf16*)As;  // 128 x 72 bf16 = 18 KB
    constexpr int EW = 72;
#pragma unroll
    for (int m = 0; m < 4; ++m)
#pragma unroll
      for (int n = 0; n < 2; ++n)
#pragma unroll
        for (int r = 0; r < 4; ++r) {
          const int row = wr * 64 + m * 16 + lhi * 4 + r;
          const int col = wc * 32 + n * 16 + l15;
          const float g = acc1[m][n][r];
          const float u = acc3[m][n][r];
          eps[row * EW + col] = (__bf16)((g / (1.f + __expf(-g))) * u * comb[row]);
        }
    __syncthreads();
#pragma unroll
    for (int p = 0; p < 4; ++p) {
      const int i = p * 256 + tid;
      const int row = i >> 3, c8 = (i & 7) * 8;
      *(bf16x8*)&hbuf[(size_t)(m0 + row) * FFN + f0 + c8] =
          *(const bf16x8*)&eps[row * EW + c8];
    }
  }
#undef G1_LOADB
#undef G1_STAGEA
#undef G1_WRITEB
#undef G1_COMPUTE
}

// ---------------- GEMM2 sparse: outp[kz][pair, d] bf16, split-K=2, fused-convert B ----------------
// B: w2 fp32 native [E][F][D]; thread (fp=tid&31, dq=tid>>5) loads f-pair rows
// {2fp,2fp+1} x 8 d-values, packs bf16x2 along f, writes [d][f] tile swizzled.
__global__ __launch_bounds__(256) void gemm2_kernel(
    const __bf16* __restrict__ hbuf, const float* __restrict__ w2,
    const int* __restrict__ sched_e, __bf16* __restrict__ outp) {
  __shared__ alignas(16) __bf16 As[2][128 * 64];
  __shared__ alignas(16) __bf16 Bs[2][64 * 64];
  const int tid = threadIdx.x;
  const int id = blockIdx.x;
  const int gk = (id & 7) + ((id >> 6) << 3);
  const int n0 = ((id >> 3) & 7) * 64;
  const int mb = gk >> 1;
  const int kz = gk & 1;
  const int e = sched_e[mb];
  if (e < 0) return;
  const int m0 = mb * 128;
  const int fbase = kz * (FFN / 2);
  const int lane = tid & 63;
  const int wv = tid >> 6;
  const int wr = wv >> 1, wc = wv & 1;
  const int l15 = lane & 15, lhi = lane >> 4;
  const int sw = (l15 & 7) << 4;
  const int fp = tid & 31, dq = tid >> 5;

  size_t aoff[4];
  int lbA[4];
#pragma unroll
  for (int it = 0; it < 4; ++it) {
    const int chunk = it * 256 + tid;
    const int r = chunk >> 3;
    const int c8 = ((chunk & 7) ^ (r & 7)) * 8;
    aoff[it] = (size_t)(m0 + r) * FFN + fbase + c8;
    lbA[it] = (it * 256 + (tid & ~63)) * 16;
  }
  const float* bbase = w2 + ((size_t)e * FFN + fbase + 2 * fp) * DMODEL + n0 + dq * 8;

  const f32x4 fz = {0.f, 0.f, 0.f, 0.f};
  f32x4 acc[4][2];
#pragma unroll
  for (int m = 0; m < 4; ++m) { acc[m][0] = fz; acc[m][1] = fz; }

  f32x4 q[4];

#define G2_LOADB(K0)                                                          \
  do {                                                                        \
    const float* p = bbase + (size_t)(K0)*DMODEL;                             \
    q[0] = *(const f32x4*)p;            q[1] = *(const f32x4*)(p + 4);        \
    q[2] = *(const f32x4*)(p + DMODEL); q[3] = *(const f32x4*)(p + DMODEL + 4);\
  } while (0)

#define G2_STAGEA(BUF, K0)                                                    \
  do {                                                                        \
    _Pragma("unroll") for (int it = 0; it < 4; ++it)                          \
        gload_lds16(hbuf + aoff[it] + (K0), (char*)As[BUF] + lbA[it]);        \
  } while (0)

#define G2_WRITEB(BUF)                                                        \
  do {                                                                        \
    _Pragma("unroll") for (int i = 0; i < 8; ++i) {                           \
      const float lo = i < 4 ? q[0][i] : q[1][i - 4];                         \
      const float hi = i < 4 ? q[2][i] : q[3][i - 4];                         \
      const int ad = (dq * 8 + i) * 128 + ((fp * 4) ^ (i << 4));              \
      bf16x2 v = {(__bf16)lo, (__bf16)hi};                                    \
      *(bf16x2*)((char*)Bs[BUF] + ad) = v;                                    \
    }                                                                         \
  } while (0)

#define G2_COMPUTE(BUF)                                                       \
  do {                                                                        \
    __builtin_amdgcn_s_setprio(1);                                            \
    _Pragma("unroll") for (int kk = 0; kk < 2; ++kk) {                        \
      const int ko = (kk * 64 + lhi * 16) ^ sw;                               \
      bf16x8 af[4], bfr[2];                                                   \
      _Pragma("unroll") for (int m = 0; m < 4; ++m)                           \
          af[m] = *(const bf16x8*)((const char*)As[BUF] +                     \
                                   (wr * 64 + m * 16 + l15) * 128 + ko);      \
      _Pragma("unroll") for (int n = 0; n < 2; ++n)                           \
          bfr[n] = *(const bf16x8*)((const char*)Bs[BUF] +                    \
                                    (wc * 32 + n * 16 + l15) * 128 + ko);     \
      _Pragma("unroll") for (int m = 0; m < 4; ++m)                           \
          _Pragma("unroll") for (int n = 0; n < 2; ++n)                       \
              acc[m][n] = __builtin_amdgcn_mfma_f32_16x16x32_bf16(            \
                  af[m], bfr[n], acc[m][n], 0, 0, 0);                         \
    }                                                                         \
    __builtin_amdgcn_s_setprio(0);                                            \
  } while (0)

  G2_LOADB(0);
  G2_STAGEA(0, 0);
  VM0();
  G2_WRITEB(0);
  LG0_BAR();
#pragma unroll
  for (int t = 0; t < 7; ++t) {
    G2_LOADB((t + 1) * 64);
    G2_STAGEA((t + 1) & 1, (t + 1) * 64);
    G2_COMPUTE(t & 1);
    VM0();
    G2_WRITEB((t + 1) & 1);
    LG0_BAR();
  }
  G2_COMPUTE(1);

  // ---- LDS-bounce epilogue ----
  __syncthreads();
  {
    __bf16* eps = (__bf16*)As;
    constexpr int EW = 72;
#pragma unroll
    for (int m = 0; m < 4; ++m)
#pragma unroll
      for (int n = 0; n < 2; ++n)
#pragma unroll
        for (int r = 0; r < 4; ++r) {
          const int row = wr * 64 + m * 16 + lhi * 4 + r;
          const int col = wc * 32 + n * 16 + l15;
          eps[row * EW + col] = (__bf16)acc[m][n][r];
        }
    __syncthreads();
#pragma unroll
    for (int p = 0; p < 4; ++p) {
      const int i = p * 256 + tid;
      const int row = i >> 3, c8 = (i & 7) * 8;
      *(bf16x8*)&outp[((size_t)kz * PCAP + m0 + row) * DMODEL + n0 + c8] =
          *(const bf16x8*)&eps[row * EW + c8];
    }
  }
#undef G2_LOADB
#undef G2_STAGEA
#undef G2_WRITEB
#undef G2_COMPUTE
}

// ---------------- gather: out[t] = sum of 2 pairs x 2 kz (bf16 partials, fp32 sum) ----------------
__global__ __launch_bounds__(256) void gather_kernel(
    const __bf16* __restrict__ outp, const int* __restrict__ pairidx,
    float* __restrict__ out) {
  const int i = blockIdx.x * 256 + threadIdx.x;
  const int t = i >> 6;
  const int c = (i & 63) * 8;
  const int p0 = pairidx[t * 2];
  const int p1 = pairidx[t * 2 + 1];
  const size_t KZ = (size_t)PCAP * DMODEL;
  const bf16x8 a0 = *(const bf16x8*)&outp[(size_t)p0 * DMODEL + c];
  const bf16x8 a1 = *(const bf16x8*)&outp[(size_t)p1 * DMODEL + c];
  const bf16x8 b0 = *(const bf16x8*)&outp[KZ + (size_t)p0 * DMODEL + c];
  const bf16x8 b1 = *(const bf16x8*)&outp[KZ + (size_t)p1 * DMODEL + c];
  f32x4 lo, hi;
#pragma unroll
  for (int j = 0; j < 4; ++j)
    lo[j] = (float)a0[j] + (float)a1[j] + (float)b0[j] + (float)b1[j];
#pragma unroll
  for (int j = 0; j < 4; ++j)
    hi[j] = (float)a0[j + 4] + (float)a1[j + 4] + (float)b0[j + 4] + (float)b1[j + 4];
  float* op = out + (size_t)t * DMODEL + c;
  *(f32x4*)op = lo;
  *(f32x4*)(op + 4) = hi;
}

extern "C" void kernel_launch(void* const* d_in, const int* in_sizes, int n_in,
                              void* d_out, int out_size, void* d_ws, size_t ws_size,
                              hipStream_t stream) {
  const float* x = (const float*)d_in[0];
  const float* rw = (const float*)d_in[1];
  const float* w1 = (const float*)d_in[2];
  const float* w2 = (const float*)d_in[3];
  const float* w3 = (const float*)d_in[4];
  float* out = (float*)d_out;
  char* ws = (char*)d_ws;

  int* tope = (int*)(ws + 0);                  //    16,384
  float* topw = (float*)(ws + 16384);          //    16,384
  int* pair_t = (int*)(ws + 32768);            //    20,480
  float* pair_w = (float*)(ws + 53248);        //    20,480
  int* pairidx = (int*)(ws + 73728);           //    16,384
  int* sched_e = (int*)(ws + 90112);           //     8,192 (padded)
  __bf16* xb = (__bf16*)(ws + 98304);          //  2,097,152
  __bf16* hbuf = (__bf16*)(ws + 2195456);      // 10,485,760 [PCAP][F]
  __bf16* outp = (__bf16*)(ws + 12681216);     // 10,485,760 [2][PCAP][D] bf16

  hipLaunchKernelGGL(prep_kernel, dim3(520), dim3(256), 0, stream,
                     x, rw, xb, tope, topw, pair_t, pair_w, sched_e);
  hipLaunchKernelGGL(build_kernel, dim3(1), dim3(256), 0, stream,
                     tope, topw, pair_t, pair_w, pairidx, sched_e);
  hipLaunchKernelGGL(gemm1_kernel, dim3(640), dim3(256), 0, stream,
                     xb, w1, w3, pair_t, pair_w, sched_e, hbuf);
  hipLaunchKernelGGL(gemm2_kernel, dim3(640), dim3(256), 0, stream,
                     hbuf, w2, sched_e, outp);
  hipLaunchKernelGGL(gather_kernel, dim3(512), dim3(256), 0, stream,
                     outp, pairidx, out);
}

// Round 11
// 75.497 us; speedup vs baseline: 1.1455x; 1.1455x over previous
//
#include <hip/hip_runtime.h>
#include <hip/hip_bf16.h>

// MoE forward, top-2 sparse gather-GEMM.
// T=2048, D=512, F=1024, E=8, top-2. fp32 in/out, bf16 MFMA internally.
//
// Round 11 = R9 (72.8us, proven) + ONE isolated change:
//  - gemm2: depth-2 pipeline (3 LDS buffers, ONE barrier/K-step, vmcnt(6)
//    steady state = two 6-load stages in flight, 2 K-steps to land each)
//  - everything else identical to R9: prep transpose+cvt_router+init, simple
//    atomic build, gemm1 depth-1 counted-vmcnt, XOR-swizzled LDS, setprio,
//    mod-8 sharing swizzle, LDS-bounce epilogues, gather.

typedef __attribute__((ext_vector_type(4))) float f32x4;
typedef __attribute__((ext_vector_type(8))) __bf16 bf16x8;

#define T_TOK 2048
#define DMODEL 512
#define FFN 1024
#define NE 8
#define MAXMB 40
#define PCAP (MAXMB * 128)

__device__ __forceinline__ void gload_lds16(const void* g, void* l) {
  __builtin_amdgcn_global_load_lds(
      (const __attribute__((address_space(1))) void*)g,
      (__attribute__((address_space(3))) void*)l, 16, 0, 0);
}

#define PIPE_BAR_8()                                        \
  asm volatile("s_waitcnt vmcnt(8)" ::: "memory");          \
  __builtin_amdgcn_s_barrier();                             \
  __builtin_amdgcn_sched_barrier(0)
#define PIPE_BAR_6()                                        \
  asm volatile("s_waitcnt vmcnt(6)" ::: "memory");          \
  __builtin_amdgcn_s_barrier();                             \
  __builtin_amdgcn_sched_barrier(0)
#define PIPE_BAR_0()                                        \
  asm volatile("s_waitcnt vmcnt(0)" ::: "memory");          \
  __builtin_amdgcn_s_barrier();                             \
  __builtin_amdgcn_sched_barrier(0)
#define POST_BAR()                                          \
  __builtin_amdgcn_s_barrier();                             \
  __builtin_amdgcn_sched_barrier(0)

// ---------------- prep: transposes + cvt_router + inits, one launch ----------------
__global__ __launch_bounds__(256) void prep_kernel(
    const float* __restrict__ x, const float* __restrict__ rw,
    const float* __restrict__ w1, const float* __restrict__ w2,
    const float* __restrict__ w3, __bf16* __restrict__ xb,
    __bf16* __restrict__ w1t, __bf16* __restrict__ w2t,
    __bf16* __restrict__ w3t, int* __restrict__ tope, float* __restrict__ topw,
    int* __restrict__ pair_t, float* __restrict__ pair_w,
    int* __restrict__ sched_e) {
  __shared__ __bf16 tile[64][65];
  const int bx = blockIdx.x;
  const int tid = threadIdx.x;

  if (bx < 3072) {
    // ---- weight transpose + cvt: src[e][R][C] f32 -> dst[e][C][R] bf16 ----
    const float* src;
    __bf16* dst;
    int R, C, idx;
    if (bx < 1024)      { src = w1; dst = w1t; R = 512;  C = 1024; idx = bx; }
    else if (bx < 2048) { src = w3; dst = w3t; R = 512;  C = 1024; idx = bx - 1024; }
    else                { src = w2; dst = w2t; R = 1024; C = 512;  idx = bx - 2048; }
    const int ntx = C >> 6, nty = R >> 6;
    const int cx = idx % ntx;
    const int gry = idx / ntx;
    const int e = gry / nty;
    const int r0 = (gry % nty) * 64;
    const int c0 = cx * 64;
    src += (size_t)e * R * C;
    dst += (size_t)e * R * C;
#pragma unroll
    for (int q = 0; q < 4; ++q) {
      const int r = (tid >> 4) + q * 16;
      const int c = (tid & 15) * 4;
      const f32x4 v = *(const f32x4*)&src[(size_t)(r0 + r) * C + c0 + c];
      tile[r][c] = (__bf16)v[0];
      tile[r][c + 1] = (__bf16)v[1];
      tile[r][c + 2] = (__bf16)v[2];
      tile[r][c + 3] = (__bf16)v[3];
    }
    __syncthreads();
#pragma unroll
    for (int p = 0; p < 2; ++p) {
      const int cc = (tid >> 3) + p * 32;
      const int rr = (tid & 7) * 8;
      union { bf16x8 v; __bf16 s[8]; } u;
#pragma unroll
      for (int i = 0; i < 8; ++i) u.s[i] = tile[rr + i][cc];
      *(bf16x8*)&dst[(size_t)(c0 + cc) * R + r0 + rr] = u.v;
    }
  } else if (bx < 3584) {
    // ---- x -> bf16 + router top-2 ----
    const int t = (bx - 3072) * 4 + (tid >> 6);
    const int lane = tid & 63;
    const float* xr = x + (size_t)t * DMODEL + lane * 8;
    const f32x4 a = *(const f32x4*)xr;
    const f32x4 b = *(const f32x4*)(xr + 4);
    bf16x8 v;
    v[0] = (__bf16)a[0]; v[1] = (__bf16)a[1]; v[2] = (__bf16)a[2]; v[3] = (__bf16)a[3];
    v[4] = (__bf16)b[0]; v[5] = (__bf16)b[1]; v[6] = (__bf16)b[2]; v[7] = (__bf16)b[3];
    *(bf16x8*)&xb[(size_t)t * DMODEL + lane * 8] = v;

    float xv[8] = {a[0], a[1], a[2], a[3], b[0], b[1], b[2], b[3]};
    float part[NE];
#pragma unroll
    for (int e = 0; e < NE; ++e) part[e] = 0.f;
#pragma unroll
    for (int i = 0; i < 8; ++i) {
      const int d = lane * 8 + i;
      const f32x4 r0 = *(const f32x4*)&rw[(size_t)d * NE];
      const f32x4 r1 = *(const f32x4*)&rw[(size_t)d * NE + 4];
      part[0] += xv[i] * r0[0]; part[1] += xv[i] * r0[1];
      part[2] += xv[i] * r0[2]; part[3] += xv[i] * r0[3];
      part[4] += xv[i] * r1[0]; part[5] += xv[i] * r1[1];
      part[6] += xv[i] * r1[2]; part[7] += xv[i] * r1[3];
    }
#pragma unroll
    for (int off = 32; off > 0; off >>= 1) {
#pragma unroll
      for (int e = 0; e < NE; ++e) part[e] += __shfl_xor(part[e], off);
    }
    if (lane == 0) {
      int ia = 0;
#pragma unroll
      for (int e = 1; e < NE; ++e)
        if (part[e] > part[ia]) ia = e;
      int ib = (ia == 0) ? 1 : 0;
#pragma unroll
      for (int e = 0; e < NE; ++e)
        if (e != ia && e != ib && part[e] > part[ib]) ib = e;
      const float wa = 1.f / (1.f + __expf(part[ib] - part[ia]));
      tope[t * 2] = ia;
      tope[t * 2 + 1] = ib;
      topw[t * 2] = wa;
      topw[t * 2 + 1] = 1.f - wa;
    }
  } else {
    // ---- init pair lists (padding rows = token 0, weight 0) + schedule ----
    const int i = (bx - 3584) * 256 + tid;  // 0..2047
    for (int j = i; j < PCAP; j += 2048) { pair_t[j] = 0; pair_w[j] = 0.f; }
    if (i < MAXMB) sched_e[i] = -1;
  }
}

// ---------------- build: count + schedule + scatter (simple-atomic) ----------------
__global__ __launch_bounds__(256) void build_kernel(
    const int* __restrict__ tope, const float* __restrict__ topw,
    int* __restrict__ pair_t, float* __restrict__ pair_w,
    int* __restrict__ pairidx, int* __restrict__ sched_e) {
  __shared__ int cnt[NE], base[NE], ofs[NE];
  const int tid = threadIdx.x;
  if (tid < NE) { cnt[tid] = 0; ofs[tid] = 0; }
  __syncthreads();
  for (int t = tid; t < T_TOK; t += 256) {
    atomicAdd(&cnt[tope[t * 2]], 1);
    atomicAdd(&cnt[tope[t * 2 + 1]], 1);
  }
  __syncthreads();
  if (tid == 0) {
    int mb = 0;
    for (int e = 0; e < NE; ++e) {
      base[e] = mb * 128;
      const int nmb = (cnt[e] + 127) >> 7;
      for (int i = 0; i < nmb; ++i) sched_e[mb + i] = e;
      mb += nmb;
    }
  }
  __syncthreads();
  for (int t = tid; t < T_TOK; t += 256) {
#pragma unroll
    for (int s = 0; s < 2; ++s) {
      const int e = tope[t * 2 + s];
      const int pos = base[e] + atomicAdd(&ofs[e], 1);
      pair_t[pos] = t;
      pair_w[pos] = topw[t * 2 + s];
      pairidx[t * 2 + s] = pos;
    }
  }
}

// ---------------- GEMM1 sparse: 128(pairs) x 64(f), BK=64, counted-vmcnt (R9) ----------------
__global__ __launch_bounds__(256) void gemm1_kernel(
    const __bf16* __restrict__ xb, const __bf16* __restrict__ w1t,
    const __bf16* __restrict__ w3t, const int* __restrict__ pair_t,
    const float* __restrict__ pair_w, const int* __restrict__ sched_e,
    __bf16* __restrict__ hbuf) {
  __shared__ alignas(16) __bf16 As[2][128 * 64];
  __shared__ alignas(16) __bf16 B1s[2][64 * 64];
  __shared__ alignas(16) __bf16 B3s[2][64 * 64];
  __shared__ float comb[128];
  const int tid = threadIdx.x;
  const int id = blockIdx.x;
  const int mb = (id & 7) + ((id >> 7) << 3);
  const int f0 = ((id >> 3) & 15) * 64;
  const int e = sched_e[mb];
  if (e < 0) return;
  const int m0 = mb * 128;
  const int lane = tid & 63;
  const int wv = tid >> 6;
  const int wr = wv >> 1, wc = wv & 1;
  const int l15 = lane & 15, lhi = lane >> 4;
  const int sw = (l15 & 7) << 4;

  if (tid < 128) comb[tid] = pair_w[m0 + tid];

  size_t aoff[4];
  int lbA[4];
#pragma unroll
  for (int it = 0; it < 4; ++it) {
    const int chunk = it * 256 + tid;
    const int r = chunk >> 3;
    const int c8 = ((chunk & 7) ^ (r & 7)) * 8;
    aoff[it] = (size_t)pair_t[m0 + r] * DMODEL + c8;
    lbA[it] = (it * 256 + (tid & ~63)) * 16;
  }
  size_t boff[2];
  int lbB[2];
#pragma unroll
  for (int it = 0; it < 2; ++it) {
    const int chunk = it * 256 + tid;
    const int r = chunk >> 3;
    const int c8 = ((chunk & 7) ^ (r & 7)) * 8;
    boff[it] = (size_t)(e * FFN + f0 + r) * DMODEL + c8;
    lbB[it] = (it * 256 + (tid & ~63)) * 16;
  }

  const f32x4 fz = {0.f, 0.f, 0.f, 0.f};
  f32x4 acc1[4][2], acc3[4][2];
#pragma unroll
  for (int m = 0; m < 4; ++m)
#pragma unroll
    for (int n = 0; n < 2; ++n) { acc1[m][n] = fz; acc3[m][n] = fz; }

#define G1_STAGE(BUF, K0)                                                     \
  do {                                                                        \
    _Pragma("unroll") for (int it = 0; it < 4; ++it)                          \
        gload_lds16(xb + aoff[it] + (K0), (char*)As[BUF] + lbA[it]);          \
    _Pragma("unroll") for (int it = 0; it < 2; ++it) {                        \
      gload_lds16(w1t + boff[it] + (K0), (char*)B1s[BUF] + lbB[it]);          \
      gload_lds16(w3t + boff[it] + (K0), (char*)B3s[BUF] + lbB[it]);          \
    }                                                                         \
  } while (0)

#define G1_COMPUTE(BUF)                                                       \
  do {                                                                        \
    __builtin_amdgcn_s_setprio(1);                                            \
    _Pragma("unroll") for (int kk = 0; kk < 2; ++kk) {                        \
      const int ko = (kk * 64 + lhi * 16) ^ sw;                               \
      bf16x8 af[4], b1f[2], b3f[2];                                           \
      _Pragma("unroll") for (int m = 0; m < 4; ++m)                           \
          af[m] = *(const bf16x8*)((const char*)As[BUF] +                     \
                                   (wr * 64 + m * 16 + l15) * 128 + ko);      \
      _Pragma("unroll") for (int n = 0; n < 2; ++n) {                         \
        const int ro = (wc * 32 + n * 16 + l15) * 128 + ko;                   \
        b1f[n] = *(const bf16x8*)((const char*)B1s[BUF] + ro);                \
        b3f[n] = *(const bf16x8*)((const char*)B3s[BUF] + ro);                \
      }                                                                       \
      _Pragma("unroll") for (int m = 0; m < 4; ++m)                           \
          _Pragma("unroll") for (int n = 0; n < 2; ++n) {                     \
        acc1[m][n] = __builtin_amdgcn_mfma_f32_16x16x32_bf16(af[m], b1f[n],   \
                                                             acc1[m][n], 0, 0, 0); \
        acc3[m][n] = __builtin_amdgcn_mfma_f32_16x16x32_bf16(af[m], b3f[n],   \
                                                             acc3[m][n], 0, 0, 0); \
      }                                                                       \
    }                                                                         \
    __builtin_amdgcn_s_setprio(0);                                            \
  } while (0)

  G1_STAGE(0, 0);
#pragma unroll
  for (int t = 0; t < 7; ++t) {
    G1_STAGE((t + 1) & 1, (t + 1) * 64);
    PIPE_BAR_8();
    G1_COMPUTE(t & 1);
    POST_BAR();
  }
  PIPE_BAR_0();
  G1_COMPUTE(1);

  // ---- LDS-bounce epilogue: silu(g)*u*w -> pad-72 scratch -> coalesced b128 ----
  __syncthreads();
  {
    __bf16* eps = (__bf16*)As;  // 128 x 72 bf16 = 18 KB
    constexpr int EW = 72;
#pragma unroll
    for (int m = 0; m < 4; ++m)
#pragma unroll
      for (int n = 0; n < 2; ++n)
#pragma unroll
        for (int r = 0; r < 4; ++r) {
          const int row = wr * 64 + m * 16 + lhi * 4 + r;
          const int col = wc * 32 + n * 16 + l15;
          const float g = acc1[m][n][r];
          const float u = acc3[m][n][r];
          eps[row * EW + col] = (__bf16)((g / (1.f + __expf(-g))) * u * comb[row]);
        }
    __syncthreads();
#pragma unroll
    for (int p = 0; p < 4; ++p) {
      const int i = p * 256 + tid;
      const int row = i >> 3, c8 = (i & 7) * 8;
      *(bf16x8*)&hbuf[(size_t)(m0 + row) * FFN + f0 + c8] =
          *(const bf16x8*)&eps[row * EW + c8];
    }
  }
#undef G1_STAGE
#undef G1_COMPUTE
}

// ---------------- GEMM2 sparse: depth-2 (3-buffer, ONE barrier/step), split-K=2 ----------------
// Hazard check: stage(t+2) at end of iter t overwrites buf (t-1)%3, whose
// readers (compute(t-1)) all passed iter-t's barrier. Each wave's vmcnt(6)
// at iter t+2 covers its own stage(t+2) loads; barrier makes them visible.
__global__ __launch_bounds__(256) void gemm2_kernel(
    const __bf16* __restrict__ hbuf, const __bf16* __restrict__ w2t,
    const int* __restrict__ sched_e, __bf16* __restrict__ outp) {
  __shared__ alignas(16) __bf16 As[3][128 * 64];
  __shared__ alignas(16) __bf16 Bs[3][64 * 64];
  const int tid = threadIdx.x;
  const int id = blockIdx.x;
  const int gk = (id & 7) + ((id >> 6) << 3);
  const int n0 = ((id >> 3) & 7) * 64;
  const int mb = gk >> 1;
  const int kz = gk & 1;
  const int e = sched_e[mb];
  if (e < 0) return;
  const int m0 = mb * 128;
  const int fbase = kz * (FFN / 2);
  const int lane = tid & 63;
  const int wv = tid >> 6;
  const int wr = wv >> 1, wc = wv & 1;
  const int l15 = lane & 15, lhi = lane >> 4;
  const int sw = (l15 & 7) << 4;

  size_t aoff[4];
  int lbA[4];
#pragma unroll
  for (int it = 0; it < 4; ++it) {
    const int chunk = it * 256 + tid;
    const int r = chunk >> 3;
    const int c8 = ((chunk & 7) ^ (r & 7)) * 8;
    aoff[it] = (size_t)(m0 + r) * FFN + fbase + c8;
    lbA[it] = (it * 256 + (tid & ~63)) * 16;
  }
  size_t boff[2];
  int lbB[2];
#pragma unroll
  for (int it = 0; it < 2; ++it) {
    const int chunk = it * 256 + tid;
    const int r = chunk >> 3;
    const int c8 = ((chunk & 7) ^ (r & 7)) * 8;
    boff[it] = ((size_t)e * DMODEL + n0 + r) * FFN + fbase + c8;
    lbB[it] = (it * 256 + (tid & ~63)) * 16;
  }

  const f32x4 fz = {0.f, 0.f, 0.f, 0.f};
  f32x4 acc[4][2];
#pragma unroll
  for (int m = 0; m < 4; ++m) { acc[m][0] = fz; acc[m][1] = fz; }

#define G2_STAGE(BUF, K0)                                                     \
  do {                                                                        \
    _Pragma("unroll") for (int it = 0; it < 4; ++it)                          \
        gload_lds16(hbuf + aoff[it] + (K0), (char*)As[BUF] + lbA[it]);        \
    _Pragma("unroll") for (int it = 0; it < 2; ++it)                          \
        gload_lds16(w2t + boff[it] + (K0), (char*)Bs[BUF] + lbB[it]);         \
  } while (0)

#define G2_COMPUTE(BUF)                                                       \
  do {                                                                        \
    __builtin_amdgcn_s_setprio(1);                                            \
    _Pragma("unroll") for (int kk = 0; kk < 2; ++kk) {                        \
      const int ko = (kk * 64 + lhi * 16) ^ sw;                               \
      bf16x8 af[4], bfr[2];                                                   \
      _Pragma("unroll") for (int m = 0; m < 4; ++m)                           \
          af[m] = *(const bf16x8*)((const char*)As[BUF] +                     \
                                   (wr * 64 + m * 16 + l15) * 128 + ko);      \
      _Pragma("unroll") for (int n = 0; n < 2; ++n)                           \
          bfr[n] = *(const bf16x8*)((const char*)Bs[BUF] +                    \
                                    (wc * 32 + n * 16 + l15) * 128 + ko);     \
      _Pragma("unroll") for (int m = 0; m < 4; ++m)                           \
          _Pragma("unroll") for (int n = 0; n < 2; ++n)                       \
              acc[m][n] = __builtin_amdgcn_mfma_f32_16x16x32_bf16(            \
                  af[m], bfr[n], acc[m][n], 0, 0, 0);                         \
    }                                                                         \
    __builtin_amdgcn_s_setprio(0);                                            \
  } while (0)

  // depth-2 prologue: two stages in flight
  G2_STAGE(0, 0);
  G2_STAGE(1, 64);
#pragma unroll
  for (int t = 0; t < 6; ++t) {
    PIPE_BAR_6();                 // stage(t) landed (newest 6 = stage(t+1))
    G2_COMPUTE(t % 3);
    G2_STAGE((t + 2) % 3, (t + 2) * 64);  // overwrites buf(t-1)%3: safe
  }
  PIPE_BAR_6();                   // stage(6) landed (stage(7) in flight)
  G2_COMPUTE(0);                  // 6 % 3
  PIPE_BAR_0();                   // stage(7) landed
  G2_COMPUTE(1);                  // 7 % 3

  // ---- LDS-bounce epilogue ----
  __syncthreads();
  {
    __bf16* eps = (__bf16*)As;
    constexpr int EW = 72;
#pragma unroll
    for (int m = 0; m < 4; ++m)
#pragma unroll
      for (int n = 0; n < 2; ++n)
#pragma unroll
        for (int r = 0; r < 4; ++r) {
          const int row = wr * 64 + m * 16 + lhi * 4 + r;
          const int col = wc * 32 + n * 16 + l15;
          eps[row * EW + col] = (__bf16)acc[m][n][r];
        }
    __syncthreads();
#pragma unroll
    for (int p = 0; p < 4; ++p) {
      const int i = p * 256 + tid;
      const int row = i >> 3, c8 = (i & 7) * 8;
      *(bf16x8*)&outp[((size_t)kz * PCAP + m0 + row) * DMODEL + n0 + c8] =
          *(const bf16x8*)&eps[row * EW + c8];
    }
  }
#undef G2_STAGE
#undef G2_COMPUTE
}

// ---------------- gather: out[t] = sum of 2 pairs x 2 kz (bf16 partials, fp32 sum) ----------------
__global__ __launch_bounds__(256) void gather_kernel(
    const __bf16* __restrict__ outp, const int* __restrict__ pairidx,
    float* __restrict__ out) {
  const int i = blockIdx.x * 256 + threadIdx.x;
  const int t = i >> 6;
  const int c = (i & 63) * 8;
  const int p0 = pairidx[t * 2];
  const int p1 = pairidx[t * 2 + 1];
  const size_t KZ = (size_t)PCAP * DMODEL;
  const bf16x8 a0 = *(const bf16x8*)&outp[(size_t)p0 * DMODEL + c];
  const bf16x8 a1 = *(const bf16x8*)&outp[(size_t)p1 * DMODEL + c];
  const bf16x8 b0 = *(const bf16x8*)&outp[KZ + (size_t)p0 * DMODEL + c];
  const bf16x8 b1 = *(const bf16x8*)&outp[KZ + (size_t)p1 * DMODEL + c];
  f32x4 lo, hi;
#pragma unroll
  for (int j = 0; j < 4; ++j)
    lo[j] = (float)a0[j] + (float)a1[j] + (float)b0[j] + (float)b1[j];
#pragma unroll
  for (int j = 0; j < 4; ++j)
    hi[j] = (float)a0[j + 4] + (float)a1[j + 4] + (float)b0[j + 4] + (float)b1[j + 4];
  float* op = out + (size_t)t * DMODEL + c;
  *(f32x4*)op = lo;
  *(f32x4*)(op + 4) = hi;
}

extern "C" void kernel_launch(void* const* d_in, const int* in_sizes, int n_in,
                              void* d_out, int out_size, void* d_ws, size_t ws_size,
                              hipStream_t stream) {
  const float* x = (const float*)d_in[0];
  const float* rw = (const float*)d_in[1];
  const float* w1 = (const float*)d_in[2];
  const float* w2 = (const float*)d_in[3];
  const float* w3 = (const float*)d_in[4];
  float* out = (float*)d_out;
  char* ws = (char*)d_ws;

  int* tope = (int*)(ws + 0);                  //    16,384
  float* topw = (float*)(ws + 16384);          //    16,384
  int* pair_t = (int*)(ws + 32768);            //    20,480
  float* pair_w = (float*)(ws + 53248);        //    20,480
  int* pairidx = (int*)(ws + 73728);           //    16,384
  int* sched_e = (int*)(ws + 90112);           //     8,192 (padded)
  __bf16* xb = (__bf16*)(ws + 98304);          // 2,097,152
  __bf16* w1t = (__bf16*)(ws + 2195456);       // 8,388,608  [E][F][D]
  __bf16* w3t = (__bf16*)(ws + 10584064);      // 8,388,608  [E][F][D]
  __bf16* w2t = (__bf16*)(ws + 18972672);      // 8,388,608  [E][D][F]
  __bf16* hbuf = (__bf16*)(ws + 27361280);     // 10,485,760 [PCAP][F]
  __bf16* outp = (__bf16*)(ws + 37847040);     // 10,485,760 [2][PCAP][D] bf16

  hipLaunchKernelGGL(prep_kernel, dim3(3592), dim3(256), 0, stream,
                     x, rw, w1, w2, w3, xb, w1t, w2t, w3t, tope, topw,
                     pair_t, pair_w, sched_e);
  hipLaunchKernelGGL(build_kernel, dim3(1), dim3(256), 0, stream,
                     tope, topw, pair_t, pair_w, pairidx, sched_e);
  hipLaunchKernelGGL(gemm1_kernel, dim3(640), dim3(256), 0, stream,
                     xb, w1t, w3t, pair_t, pair_w, sched_e, hbuf);
  hipLaunchKernelGGL(gemm2_kernel, dim3(640), dim3(256), 0, stream,
                     hbuf, w2t, sched_e, outp);
  hipLaunchKernelGGL(gather_kernel, dim3(512), dim3(256), 0, stream,
                     outp, pairidx, out);
}

// Round 12
// 70.496 us; speedup vs baseline: 1.2267x; 1.0709x over previous
//
#include <hip/hip_runtime.h>
#include <hip/hip_bf16.h>

// MoE forward, top-2 sparse gather-GEMM.
// T=2048, D=512, F=1024, E=8, top-2. fp32 in/out, bf16 MFMA internally.
//
// Round 12 = R9 (72.8us) + ONE isolated change: BK 64->32 in both GEMMs.
//  - gemm1 LDS 64.5KB->33KB (2->up to 4 blocks/CU), gemm2 48KB->24KB (3->up to 6)
//  - 16 K-steps, 4 (gemm1) / 3 (gemm2) loads per stage, vmcnt(4)/vmcnt(3)
//  - swizzle for 64B rows: src col (chunk&3)^((r>>1)&3), read ko=(lhi^((l15>>1)&3))<<4
//  - single smem char array partitioned manually (epilogue bounce needs 18KB)
//  - occupancy>depth rule from R11; everything else identical to R9

typedef __attribute__((ext_vector_type(4))) float f32x4;
typedef __attribute__((ext_vector_type(8))) __bf16 bf16x8;

#define T_TOK 2048
#define DMODEL 512
#define FFN 1024
#define NE 8
#define MAXMB 40
#define PCAP (MAXMB * 128)

__device__ __forceinline__ void gload_lds16(const void* g, void* l) {
  __builtin_amdgcn_global_load_lds(
      (const __attribute__((address_space(1))) void*)g,
      (__attribute__((address_space(3))) void*)l, 16, 0, 0);
}

#define PIPE_BAR_4()                                        \
  asm volatile("s_waitcnt vmcnt(4)" ::: "memory");          \
  __builtin_amdgcn_s_barrier();                             \
  __builtin_amdgcn_sched_barrier(0)
#define PIPE_BAR_3()                                        \
  asm volatile("s_waitcnt vmcnt(3)" ::: "memory");          \
  __builtin_amdgcn_s_barrier();                             \
  __builtin_amdgcn_sched_barrier(0)
#define PIPE_BAR_0()                                        \
  asm volatile("s_waitcnt vmcnt(0)" ::: "memory");          \
  __builtin_amdgcn_s_barrier();                             \
  __builtin_amdgcn_sched_barrier(0)
#define POST_BAR()                                          \
  __builtin_amdgcn_s_barrier();                             \
  __builtin_amdgcn_sched_barrier(0)

// ---------------- prep: transposes + cvt_router + inits, one launch (R9) ----------------
__global__ __launch_bounds__(256) void prep_kernel(
    const float* __restrict__ x, const float* __restrict__ rw,
    const float* __restrict__ w1, const float* __restrict__ w2,
    const float* __restrict__ w3, __bf16* __restrict__ xb,
    __bf16* __restrict__ w1t, __bf16* __restrict__ w2t,
    __bf16* __restrict__ w3t, int* __restrict__ tope, float* __restrict__ topw,
    int* __restrict__ pair_t, float* __restrict__ pair_w,
    int* __restrict__ sched_e) {
  __shared__ __bf16 tile[64][65];
  const int bx = blockIdx.x;
  const int tid = threadIdx.x;

  if (bx < 3072) {
    const float* src;
    __bf16* dst;
    int R, C, idx;
    if (bx < 1024)      { src = w1; dst = w1t; R = 512;  C = 1024; idx = bx; }
    else if (bx < 2048) { src = w3; dst = w3t; R = 512;  C = 1024; idx = bx - 1024; }
    else                { src = w2; dst = w2t; R = 1024; C = 512;  idx = bx - 2048; }
    const int ntx = C >> 6, nty = R >> 6;
    const int cx = idx % ntx;
    const int gry = idx / ntx;
    const int e = gry / nty;
    const int r0 = (gry % nty) * 64;
    const int c0 = cx * 64;
    src += (size_t)e * R * C;
    dst += (size_t)e * R * C;
#pragma unroll
    for (int q = 0; q < 4; ++q) {
      const int r = (tid >> 4) + q * 16;
      const int c = (tid & 15) * 4;
      const f32x4 v = *(const f32x4*)&src[(size_t)(r0 + r) * C + c0 + c];
      tile[r][c] = (__bf16)v[0];
      tile[r][c + 1] = (__bf16)v[1];
      tile[r][c + 2] = (__bf16)v[2];
      tile[r][c + 3] = (__bf16)v[3];
    }
    __syncthreads();
#pragma unroll
    for (int p = 0; p < 2; ++p) {
      const int cc = (tid >> 3) + p * 32;
      const int rr = (tid & 7) * 8;
      union { bf16x8 v; __bf16 s[8]; } u;
#pragma unroll
      for (int i = 0; i < 8; ++i) u.s[i] = tile[rr + i][cc];
      *(bf16x8*)&dst[(size_t)(c0 + cc) * R + r0 + rr] = u.v;
    }
  } else if (bx < 3584) {
    const int t = (bx - 3072) * 4 + (tid >> 6);
    const int lane = tid & 63;
    const float* xr = x + (size_t)t * DMODEL + lane * 8;
    const f32x4 a = *(const f32x4*)xr;
    const f32x4 b = *(const f32x4*)(xr + 4);
    bf16x8 v;
    v[0] = (__bf16)a[0]; v[1] = (__bf16)a[1]; v[2] = (__bf16)a[2]; v[3] = (__bf16)a[3];
    v[4] = (__bf16)b[0]; v[5] = (__bf16)b[1]; v[6] = (__bf16)b[2]; v[7] = (__bf16)b[3];
    *(bf16x8*)&xb[(size_t)t * DMODEL + lane * 8] = v;

    float xv[8] = {a[0], a[1], a[2], a[3], b[0], b[1], b[2], b[3]};
    float part[NE];
#pragma unroll
    for (int e = 0; e < NE; ++e) part[e] = 0.f;
#pragma unroll
    for (int i = 0; i < 8; ++i) {
      const int d = lane * 8 + i;
      const f32x4 r0 = *(const f32x4*)&rw[(size_t)d * NE];
      const f32x4 r1 = *(const f32x4*)&rw[(size_t)d * NE + 4];
      part[0] += xv[i] * r0[0]; part[1] += xv[i] * r0[1];
      part[2] += xv[i] * r0[2]; part[3] += xv[i] * r0[3];
      part[4] += xv[i] * r1[0]; part[5] += xv[i] * r1[1];
      part[6] += xv[i] * r1[2]; part[7] += xv[i] * r1[3];
    }
#pragma unroll
    for (int off = 32; off > 0; off >>= 1) {
#pragma unroll
      for (int e = 0; e < NE; ++e) part[e] += __shfl_xor(part[e], off);
    }
    if (lane == 0) {
      int ia = 0;
#pragma unroll
      for (int e = 1; e < NE; ++e)
        if (part[e] > part[ia]) ia = e;
      int ib = (ia == 0) ? 1 : 0;
#pragma unroll
      for (int e = 0; e < NE; ++e)
        if (e != ia && e != ib && part[e] > part[ib]) ib = e;
      const float wa = 1.f / (1.f + __expf(part[ib] - part[ia]));
      tope[t * 2] = ia;
      tope[t * 2 + 1] = ib;
      topw[t * 2] = wa;
      topw[t * 2 + 1] = 1.f - wa;
    }
  } else {
    const int i = (bx - 3584) * 256 + tid;
    for (int j = i; j < PCAP; j += 2048) { pair_t[j] = 0; pair_w[j] = 0.f; }
    if (i < MAXMB) sched_e[i] = -1;
  }
}

// ---------------- build: count + schedule + scatter (simple-atomic, R9) ----------------
__global__ __launch_bounds__(256) void build_kernel(
    const int* __restrict__ tope, const float* __restrict__ topw,
    int* __restrict__ pair_t, float* __restrict__ pair_w,
    int* __restrict__ pairidx, int* __restrict__ sched_e) {
  __shared__ int cnt[NE], base[NE], ofs[NE];
  const int tid = threadIdx.x;
  if (tid < NE) { cnt[tid] = 0; ofs[tid] = 0; }
  __syncthreads();
  for (int t = tid; t < T_TOK; t += 256) {
    atomicAdd(&cnt[tope[t * 2]], 1);
    atomicAdd(&cnt[tope[t * 2 + 1]], 1);
  }
  __syncthreads();
  if (tid == 0) {
    int mb = 0;
    for (int e = 0; e < NE; ++e) {
      base[e] = mb * 128;
      const int nmb = (cnt[e] + 127) >> 7;
      for (int i = 0; i < nmb; ++i) sched_e[mb + i] = e;
      mb += nmb;
    }
  }
  __syncthreads();
  for (int t = tid; t < T_TOK; t += 256) {
#pragma unroll
    for (int s = 0; s < 2; ++s) {
      const int e = tope[t * 2 + s];
      const int pos = base[e] + atomicAdd(&ofs[e], 1);
      pair_t[pos] = t;
      pair_w[pos] = topw[t * 2 + s];
      pairidx[t * 2 + s] = pos;
    }
  }
}

// ---------------- GEMM1 sparse: 128(pairs) x 64(f), BK=32, counted-vmcnt ----------------
// LDS 33.3KB: As 2x8KB | B1s 2x4KB | B3s 2x4KB | comb 512B. 16 K-steps.
__global__ __launch_bounds__(256) void gemm1_kernel(
    const __bf16* __restrict__ xb, const __bf16* __restrict__ w1t,
    const __bf16* __restrict__ w3t, const int* __restrict__ pair_t,
    const float* __restrict__ pair_w, const int* __restrict__ sched_e,
    __bf16* __restrict__ hbuf) {
  __shared__ alignas(16) char smem[33280];
#define AS_BUF(b) (smem + (b)*8192)
#define B1S_BUF(b) (smem + 16384 + (b)*4096)
#define B3S_BUF(b) (smem + 24576 + (b)*4096)
  float* comb = (float*)(smem + 32768);
  const int tid = threadIdx.x;
  const int id = blockIdx.x;
  const int mb = (id & 7) + ((id >> 7) << 3);
  const int f0 = ((id >> 3) & 15) * 64;
  const int e = sched_e[mb];
  if (e < 0) return;
  const int m0 = mb * 128;
  const int lane = tid & 63;
  const int wv = tid >> 6;
  const int wr = wv >> 1, wc = wv & 1;
  const int l15 = lane & 15, lhi = lane >> 4;
  const int ko = (lhi ^ ((l15 >> 1) & 3)) << 4;  // swizzled k-slot (64B rows)

  if (tid < 128) comb[tid] = pair_w[m0 + tid];

  // A staging: 128 rows x 32 cols; 2 chunks/thread; 4 slots/row
  size_t aoff[2];
  int lbA[2];
#pragma unroll
  for (int it = 0; it < 2; ++it) {
    const int chunk = it * 256 + tid;
    const int r = chunk >> 2;
    const int c8 = ((chunk & 3) ^ ((r >> 1) & 3)) * 8;
    aoff[it] = (size_t)pair_t[m0 + r] * DMODEL + c8;
    lbA[it] = (it * 256 + (tid & ~63)) * 16;
  }
  // B staging: 64 rows x 32 cols; 1 chunk/thread
  size_t boff;
  int lbB;
  {
    const int r = tid >> 2;
    const int c8 = ((tid & 3) ^ ((r >> 1) & 3)) * 8;
    boff = (size_t)(e * FFN + f0 + r) * DMODEL + c8;
    lbB = (tid & ~63) * 16;
  }

  const f32x4 fz = {0.f, 0.f, 0.f, 0.f};
  f32x4 acc1[4][2], acc3[4][2];
#pragma unroll
  for (int m = 0; m < 4; ++m)
#pragma unroll
    for (int n = 0; n < 2; ++n) { acc1[m][n] = fz; acc3[m][n] = fz; }

#define G1_STAGE(BUF, K0)                                                     \
  do {                                                                        \
    _Pragma("unroll") for (int it = 0; it < 2; ++it)                          \
        gload_lds16(xb + aoff[it] + (K0), AS_BUF(BUF) + lbA[it]);             \
    gload_lds16(w1t + boff + (K0), B1S_BUF(BUF) + lbB);                       \
    gload_lds16(w3t + boff + (K0), B3S_BUF(BUF) + lbB);                       \
  } while (0)

#define G1_COMPUTE(BUF)                                                       \
  do {                                                                        \
    __builtin_amdgcn_s_setprio(1);                                            \
    bf16x8 af[4], b1f[2], b3f[2];                                             \
    _Pragma("unroll") for (int m = 0; m < 4; ++m)                             \
        af[m] = *(const bf16x8*)(AS_BUF(BUF) +                                \
                                 (wr * 64 + m * 16 + l15) * 64 + ko);         \
    _Pragma("unroll") for (int n = 0; n < 2; ++n) {                           \
      const int ro = (wc * 32 + n * 16 + l15) * 64 + ko;                      \
      b1f[n] = *(const bf16x8*)(B1S_BUF(BUF) + ro);                           \
      b3f[n] = *(const bf16x8*)(B3S_BUF(BUF) + ro);                           \
    }                                                                         \
    _Pragma("unroll") for (int m = 0; m < 4; ++m)                             \
        _Pragma("unroll") for (int n = 0; n < 2; ++n) {                       \
      acc1[m][n] = __builtin_amdgcn_mfma_f32_16x16x32_bf16(af[m], b1f[n],     \
                                                           acc1[m][n], 0, 0, 0); \
      acc3[m][n] = __builtin_amdgcn_mfma_f32_16x16x32_bf16(af[m], b3f[n],     \
                                                           acc3[m][n], 0, 0, 0); \
    }                                                                         \
    __builtin_amdgcn_s_setprio(0);                                            \
  } while (0)

  G1_STAGE(0, 0);
#pragma unroll
  for (int t = 0; t < 15; ++t) {
    G1_STAGE((t + 1) & 1, (t + 1) * 32);
    PIPE_BAR_4();
    G1_COMPUTE(t & 1);
    POST_BAR();
  }
  PIPE_BAR_0();
  G1_COMPUTE(1);

  // ---- LDS-bounce epilogue: pad-72 scratch (18KB at smem base) ----
  __syncthreads();
  {
    __bf16* eps = (__bf16*)smem;
    constexpr int EW = 72;
#pragma unroll
    for (int m = 0; m < 4; ++m)
#pragma unroll
      for (int n = 0; n < 2; ++n)
#pragma unroll
        for (int r = 0; r < 4; ++r) {
          const int row = wr * 64 + m * 16 + lhi * 4 + r;
          const int col = wc * 32 + n * 16 + l15;
          const float g = acc1[m][n][r];
          const float u = acc3[m][n][r];
          eps[row * EW + col] = (__bf16)((g / (1.f + __expf(-g))) * u * comb[row]);
        }
    __syncthreads();
#pragma unroll
    for (int p = 0; p < 4; ++p) {
      const int i = p * 256 + tid;
      const int row = i >> 3, c8 = (i & 7) * 8;
      *(bf16x8*)&hbuf[(size_t)(m0 + row) * FFN + f0 + c8] =
          *(const bf16x8*)&eps[row * EW + c8];
    }
  }
#undef G1_STAGE
#undef G1_COMPUTE
#undef AS_BUF
#undef B1S_BUF
#undef B3S_BUF
}

// ---------------- GEMM2 sparse: 128x64, BK=32, split-K=2, counted-vmcnt ----------------
// LDS 24KB: As 2x8KB | Bs 2x4KB. 16 K-steps.
__global__ __launch_bounds__(256) void gemm2_kernel(
    const __bf16* __restrict__ hbuf, const __bf16* __restrict__ w2t,
    const int* __restrict__ sched_e, __bf16* __restrict__ outp) {
  __shared__ alignas(16) char smem[24576];
#define AS_BUF(b) (smem + (b)*8192)
#define BS_BUF(b) (smem + 16384 + (b)*4096)
  const int tid = threadIdx.x;
  const int id = blockIdx.x;
  const int gk = (id & 7) + ((id >> 6) << 3);
  const int n0 = ((id >> 3) & 7) * 64;
  const int mb = gk >> 1;
  const int kz = gk & 1;
  const int e = sched_e[mb];
  if (e < 0) return;
  const int m0 = mb * 128;
  const int fbase = kz * (FFN / 2);
  const int lane = tid & 63;
  const int wv = tid >> 6;
  const int wr = wv >> 1, wc = wv & 1;
  const int l15 = lane & 15, lhi = lane >> 4;
  const int ko = (lhi ^ ((l15 >> 1) & 3)) << 4;

  size_t aoff[2];
  int lbA[2];
#pragma unroll
  for (int it = 0; it < 2; ++it) {
    const int chunk = it * 256 + tid;
    const int r = chunk >> 2;
    const int c8 = ((chunk & 3) ^ ((r >> 1) & 3)) * 8;
    aoff[it] = (size_t)(m0 + r) * FFN + fbase + c8;
    lbA[it] = (it * 256 + (tid & ~63)) * 16;
  }
  size_t boff;
  int lbB;
  {
    const int r = tid >> 2;
    const int c8 = ((tid & 3) ^ ((r >> 1) & 3)) * 8;
    boff = ((size_t)e * DMODEL + n0 + r) * FFN + fbase + c8;
    lbB = (tid & ~63) * 16;
  }

  const f32x4 fz = {0.f, 0.f, 0.f, 0.f};
  f32x4 acc[4][2];
#pragma unroll
  for (int m = 0; m < 4; ++m) { acc[m][0] = fz; acc[m][1] = fz; }

#define G2_STAGE(BUF, K0)                                                     \
  do {                                                                        \
    _Pragma("unroll") for (int it = 0; it < 2; ++it)                          \
        gload_lds16(hbuf + aoff[it] + (K0), AS_BUF(BUF) + lbA[it]);           \
    gload_lds16(w2t + boff + (K0), BS_BUF(BUF) + lbB);                        \
  } while (0)

#define G2_COMPUTE(BUF)                                                       \
  do {                                                                        \
    __builtin_amdgcn_s_setprio(1);                                            \
    bf16x8 af[4], bfr[2];                                                     \
    _Pragma("unroll") for (int m = 0; m < 4; ++m)                             \
        af[m] = *(const bf16x8*)(AS_BUF(BUF) +                                \
                                 (wr * 64 + m * 16 + l15) * 64 + ko);         \
    _Pragma("unroll") for (int n = 0; n < 2; ++n)                             \
        bfr[n] = *(const bf16x8*)(BS_BUF(BUF) +                               \
                                  (wc * 32 + n * 16 + l15) * 64 + ko);        \
    _Pragma("unroll") for (int m = 0; m < 4; ++m)                             \
        _Pragma("unroll") for (int n = 0; n < 2; ++n)                         \
            acc[m][n] = __builtin_amdgcn_mfma_f32_16x16x32_bf16(              \
                af[m], bfr[n], acc[m][n], 0, 0, 0);                           \
    __builtin_amdgcn_s_setprio(0);                                            \
  } while (0)

  G2_STAGE(0, 0);
#pragma unroll
  for (int t = 0; t < 15; ++t) {
    G2_STAGE((t + 1) & 1, (t + 1) * 32);
    PIPE_BAR_3();
    G2_COMPUTE(t & 1);
    POST_BAR();
  }
  PIPE_BAR_0();
  G2_COMPUTE(1);

  // ---- LDS-bounce epilogue ----
  __syncthreads();
  {
    __bf16* eps = (__bf16*)smem;
    constexpr int EW = 72;
#pragma unroll
    for (int m = 0; m < 4; ++m)
#pragma unroll
      for (int n = 0; n < 2; ++n)
#pragma unroll
        for (int r = 0; r < 4; ++r) {
          const int row = wr * 64 + m * 16 + lhi * 4 + r;
          const int col = wc * 32 + n * 16 + l15;
          eps[row * EW + col] = (__bf16)acc[m][n][r];
        }
    __syncthreads();
#pragma unroll
    for (int p = 0; p < 4; ++p) {
      const int i = p * 256 + tid;
      const int row = i >> 3, c8 = (i & 7) * 8;
      *(bf16x8*)&outp[((size_t)kz * PCAP + m0 + row) * DMODEL + n0 + c8] =
          *(const bf16x8*)&eps[row * EW + c8];
    }
  }
#undef G2_STAGE
#undef G2_COMPUTE
#undef AS_BUF
#undef BS_BUF
}

// ---------------- gather: out[t] = sum of 2 pairs x 2 kz ----------------
__global__ __launch_bounds__(256) void gather_kernel(
    const __bf16* __restrict__ outp, const int* __restrict__ pairidx,
    float* __restrict__ out) {
  const int i = blockIdx.x * 256 + threadIdx.x;
  const int t = i >> 6;
  const int c = (i & 63) * 8;
  const int p0 = pairidx[t * 2];
  const int p1 = pairidx[t * 2 + 1];
  const size_t KZ = (size_t)PCAP * DMODEL;
  const bf16x8 a0 = *(const bf16x8*)&outp[(size_t)p0 * DMODEL + c];
  const bf16x8 a1 = *(const bf16x8*)&outp[(size_t)p1 * DMODEL + c];
  const bf16x8 b0 = *(const bf16x8*)&outp[KZ + (size_t)p0 * DMODEL + c];
  const bf16x8 b1 = *(const bf16x8*)&outp[KZ + (size_t)p1 * DMODEL + c];
  f32x4 lo, hi;
#pragma unroll
  for (int j = 0; j < 4; ++j)
    lo[j] = (float)a0[j] + (float)a1[j] + (float)b0[j] + (float)b1[j];
#pragma unroll
  for (int j = 0; j < 4; ++j)
    hi[j] = (float)a0[j + 4] + (float)a1[j + 4] + (float)b0[j + 4] + (float)b1[j + 4];
  float* op = out + (size_t)t * DMODEL + c;
  *(f32x4*)op = lo;
  *(f32x4*)(op + 4) = hi;
}

extern "C" void kernel_launch(void* const* d_in, const int* in_sizes, int n_in,
                              void* d_out, int out_size, void* d_ws, size_t ws_size,
                              hipStream_t stream) {
  const float* x = (const float*)d_in[0];
  const float* rw = (const float*)d_in[1];
  const float* w1 = (const float*)d_in[2];
  const float* w2 = (const float*)d_in[3];
  const float* w3 = (const float*)d_in[4];
  float* out = (float*)d_out;
  char* ws = (char*)d_ws;

  int* tope = (int*)(ws + 0);                  //    16,384
  float* topw = (float*)(ws + 16384);          //    16,384
  int* pair_t = (int*)(ws + 32768);            //    20,480
  float* pair_w = (float*)(ws + 53248);        //    20,480
  int* pairidx = (int*)(ws + 73728);           //    16,384
  int* sched_e = (int*)(ws + 90112);           //     8,192 (padded)
  __bf16* xb = (__bf16*)(ws + 98304);          // 2,097,152
  __bf16* w1t = (__bf16*)(ws + 2195456);       // 8,388,608  [E][F][D]
  __bf16* w3t = (__bf16*)(ws + 10584064);      // 8,388,608  [E][F][D]
  __bf16* w2t = (__bf16*)(ws + 18972672);      // 8,388,608  [E][D][F]
  __bf16* hbuf = (__bf16*)(ws + 27361280);     // 10,485,760 [PCAP][F]
  __bf16* outp = (__bf16*)(ws + 37847040);     // 10,485,760 [2][PCAP][D] bf16

  hipLaunchKernelGGL(prep_kernel, dim3(3592), dim3(256), 0, stream,
                     x, rw, w1, w2, w3, xb, w1t, w2t, w3t, tope, topw,
                     pair_t, pair_w, sched_e);
  hipLaunchKernelGGL(build_kernel, dim3(1), dim3(256), 0, stream,
                     tope, topw, pair_t, pair_w, pairidx, sched_e);
  hipLaunchKernelGGL(gemm1_kernel, dim3(640), dim3(256), 0, stream,
                     xb, w1t, w3t, pair_t, pair_w, sched_e, hbuf);
  hipLaunchKernelGGL(gemm2_kernel, dim3(640), dim3(256), 0, stream,
                     hbuf, w2t, sched_e, outp);
  hipLaunchKernelGGL(gather_kernel, dim3(512), dim3(256), 0, stream,
                     outp, pairidx, out);
}

// Round 13
// 69.371 us; speedup vs baseline: 1.2466x; 1.0162x over previous
//
#include <hip/hip_runtime.h>
#include <hip/hip_bf16.h>

// MoE forward, top-2 sparse gather-GEMM.
// T=2048, D=512, F=1024, E=8, top-2. fp32 in/out, bf16 MFMA internally.
//
// Round 13 = R12 (70.5us) + ONE scheduling change: w2-transpose co-launched
// with build (blocks 0..1023 = w2 tiles, block 1024 = build) so the 1-block
// build no longer serializes the device; prep shrinks to w1/w3+router+init.
// GEMM kernels byte-identical to R12 (BK=32, counted-vmcnt, XOR-swizzle).

typedef __attribute__((ext_vector_type(4))) float f32x4;
typedef __attribute__((ext_vector_type(8))) __bf16 bf16x8;

#define T_TOK 2048
#define DMODEL 512
#define FFN 1024
#define NE 8
#define MAXMB 40
#define PCAP (MAXMB * 128)

__device__ __forceinline__ void gload_lds16(const void* g, void* l) {
  __builtin_amdgcn_global_load_lds(
      (const __attribute__((address_space(1))) void*)g,
      (__attribute__((address_space(3))) void*)l, 16, 0, 0);
}

#define PIPE_BAR_4()                                        \
  asm volatile("s_waitcnt vmcnt(4)" ::: "memory");          \
  __builtin_amdgcn_s_barrier();                             \
  __builtin_amdgcn_sched_barrier(0)
#define PIPE_BAR_3()                                        \
  asm volatile("s_waitcnt vmcnt(3)" ::: "memory");          \
  __builtin_amdgcn_s_barrier();                             \
  __builtin_amdgcn_sched_barrier(0)
#define PIPE_BAR_0()                                        \
  asm volatile("s_waitcnt vmcnt(0)" ::: "memory");          \
  __builtin_amdgcn_s_barrier();                             \
  __builtin_amdgcn_sched_barrier(0)
#define POST_BAR()                                          \
  __builtin_amdgcn_s_barrier();                             \
  __builtin_amdgcn_sched_barrier(0)

// ---------------- prep: w1/w3 transposes + cvt_router + inits ----------------
__global__ __launch_bounds__(256) void prep_kernel(
    const float* __restrict__ x, const float* __restrict__ rw,
    const float* __restrict__ w1, const float* __restrict__ w3,
    __bf16* __restrict__ xb, __bf16* __restrict__ w1t,
    __bf16* __restrict__ w3t, int* __restrict__ tope, float* __restrict__ topw,
    int* __restrict__ pair_t, float* __restrict__ pair_w,
    int* __restrict__ sched_e) {
  const int bx = blockIdx.x;
  const int tid = threadIdx.x;

  if (bx < 2048) {
    // ---- w1/w3 transpose + cvt: src[e][512][1024] f32 -> dst[e][1024][512] bf16 ----
    __shared__ __bf16 tile[64][65];
    const float* src;
    __bf16* dst;
    int idx;
    if (bx < 1024) { src = w1; dst = w1t; idx = bx; }
    else           { src = w3; dst = w3t; idx = bx - 1024; }
    const int R = 512, C = 1024;
    const int ntx = C >> 6, nty = R >> 6;
    const int cx = idx % ntx;
    const int gry = idx / ntx;
    const int e = gry / nty;
    const int r0 = (gry % nty) * 64;
    const int c0 = cx * 64;
    src += (size_t)e * R * C;
    dst += (size_t)e * R * C;
#pragma unroll
    for (int q = 0; q < 4; ++q) {
      const int r = (tid >> 4) + q * 16;
      const int c = (tid & 15) * 4;
      const f32x4 v = *(const f32x4*)&src[(size_t)(r0 + r) * C + c0 + c];
      tile[r][c] = (__bf16)v[0];
      tile[r][c + 1] = (__bf16)v[1];
      tile[r][c + 2] = (__bf16)v[2];
      tile[r][c + 3] = (__bf16)v[3];
    }
    __syncthreads();
#pragma unroll
    for (int p = 0; p < 2; ++p) {
      const int cc = (tid >> 3) + p * 32;
      const int rr = (tid & 7) * 8;
      union { bf16x8 v; __bf16 s[8]; } u;
#pragma unroll
      for (int i = 0; i < 8; ++i) u.s[i] = tile[rr + i][cc];
      *(bf16x8*)&dst[(size_t)(c0 + cc) * R + r0 + rr] = u.v;
    }
  } else if (bx < 2560) {
    // ---- x -> bf16 + router top-2 ----
    const int t = (bx - 2048) * 4 + (tid >> 6);
    const int lane = tid & 63;
    const float* xr = x + (size_t)t * DMODEL + lane * 8;
    const f32x4 a = *(const f32x4*)xr;
    const f32x4 b = *(const f32x4*)(xr + 4);
    bf16x8 v;
    v[0] = (__bf16)a[0]; v[1] = (__bf16)a[1]; v[2] = (__bf16)a[2]; v[3] = (__bf16)a[3];
    v[4] = (__bf16)b[0]; v[5] = (__bf16)b[1]; v[6] = (__bf16)b[2]; v[7] = (__bf16)b[3];
    *(bf16x8*)&xb[(size_t)t * DMODEL + lane * 8] = v;

    float xv[8] = {a[0], a[1], a[2], a[3], b[0], b[1], b[2], b[3]};
    float part[NE];
#pragma unroll
    for (int e = 0; e < NE; ++e) part[e] = 0.f;
#pragma unroll
    for (int i = 0; i < 8; ++i) {
      const int d = lane * 8 + i;
      const f32x4 r0 = *(const f32x4*)&rw[(size_t)d * NE];
      const f32x4 r1 = *(const f32x4*)&rw[(size_t)d * NE + 4];
      part[0] += xv[i] * r0[0]; part[1] += xv[i] * r0[1];
      part[2] += xv[i] * r0[2]; part[3] += xv[i] * r0[3];
      part[4] += xv[i] * r1[0]; part[5] += xv[i] * r1[1];
      part[6] += xv[i] * r1[2]; part[7] += xv[i] * r1[3];
    }
#pragma unroll
    for (int off = 32; off > 0; off >>= 1) {
#pragma unroll
      for (int e = 0; e < NE; ++e) part[e] += __shfl_xor(part[e], off);
    }
    if (lane == 0) {
      int ia = 0;
#pragma unroll
      for (int e = 1; e < NE; ++e)
        if (part[e] > part[ia]) ia = e;
      int ib = (ia == 0) ? 1 : 0;
#pragma unroll
      for (int e = 0; e < NE; ++e)
        if (e != ia && e != ib && part[e] > part[ib]) ib = e;
      const float wa = 1.f / (1.f + __expf(part[ib] - part[ia]));
      tope[t * 2] = ia;
      tope[t * 2 + 1] = ib;
      topw[t * 2] = wa;
      topw[t * 2 + 1] = 1.f - wa;
    }
  } else {
    // ---- init pair lists (padding rows = token 0, weight 0) + schedule ----
    const int i = (bx - 2560) * 256 + tid;  // 0..2047
    for (int j = i; j < PCAP; j += 2048) { pair_t[j] = 0; pair_w[j] = 0.f; }
    if (i < MAXMB) sched_e[i] = -1;
  }
}

// ---------------- build + w2 transpose co-launched ----------------
// blocks 0..1023: w2[e][1024][512] f32 -> w2t[e][512][1024] bf16 tiles
// block 1024: build (count + schedule + scatter) — independent of w2t
__global__ __launch_bounds__(256) void build_w2t_kernel(
    const float* __restrict__ w2, __bf16* __restrict__ w2t,
    const int* __restrict__ tope, const float* __restrict__ topw,
    int* __restrict__ pair_t, float* __restrict__ pair_w,
    int* __restrict__ pairidx, int* __restrict__ sched_e) {
  const int bx = blockIdx.x;
  const int tid = threadIdx.x;
  if (bx < 1024) {
    __shared__ __bf16 tile[64][65];
    const int R = 1024, C = 512;
    const int ntx = C >> 6, nty = R >> 6;
    const int cx = bx % ntx;
    const int gry = bx / ntx;
    const int e = gry / nty;
    const int r0 = (gry % nty) * 64;
    const int c0 = cx * 64;
    const float* src = w2 + (size_t)e * R * C;
    __bf16* dst = w2t + (size_t)e * R * C;
#pragma unroll
    for (int q = 0; q < 4; ++q) {
      const int r = (tid >> 4) + q * 16;
      const int c = (tid & 15) * 4;
      const f32x4 v = *(const f32x4*)&src[(size_t)(r0 + r) * C + c0 + c];
      tile[r][c] = (__bf16)v[0];
      tile[r][c + 1] = (__bf16)v[1];
      tile[r][c + 2] = (__bf16)v[2];
      tile[r][c + 3] = (__bf16)v[3];
    }
    __syncthreads();
#pragma unroll
    for (int p = 0; p < 2; ++p) {
      const int cc = (tid >> 3) + p * 32;
      const int rr = (tid & 7) * 8;
      union { bf16x8 v; __bf16 s[8]; } u;
#pragma unroll
      for (int i = 0; i < 8; ++i) u.s[i] = tile[rr + i][cc];
      *(bf16x8*)&dst[(size_t)(c0 + cc) * R + r0 + rr] = u.v;
    }
  } else {
    // ---- build ----
    __shared__ int cnt[NE], base[NE], ofs[NE];
    if (tid < NE) { cnt[tid] = 0; ofs[tid] = 0; }
    __syncthreads();
    for (int t = tid; t < T_TOK; t += 256) {
      atomicAdd(&cnt[tope[t * 2]], 1);
      atomicAdd(&cnt[tope[t * 2 + 1]], 1);
    }
    __syncthreads();
    if (tid == 0) {
      int mb = 0;
      for (int e = 0; e < NE; ++e) {
        base[e] = mb * 128;
        const int nmb = (cnt[e] + 127) >> 7;
        for (int i = 0; i < nmb; ++i) sched_e[mb + i] = e;
        mb += nmb;
      }
    }
    __syncthreads();
    for (int t = tid; t < T_TOK; t += 256) {
#pragma unroll
      for (int s = 0; s < 2; ++s) {
        const int e = tope[t * 2 + s];
        const int pos = base[e] + atomicAdd(&ofs[e], 1);
        pair_t[pos] = t;
        pair_w[pos] = topw[t * 2 + s];
        pairidx[t * 2 + s] = pos;
      }
    }
  }
}

// ---------------- GEMM1 sparse: 128(pairs) x 64(f), BK=32, counted-vmcnt (R12) ----------------
__global__ __launch_bounds__(256) void gemm1_kernel(
    const __bf16* __restrict__ xb, const __bf16* __restrict__ w1t,
    const __bf16* __restrict__ w3t, const int* __restrict__ pair_t,
    const float* __restrict__ pair_w, const int* __restrict__ sched_e,
    __bf16* __restrict__ hbuf) {
  __shared__ alignas(16) char smem[33280];
#define AS_BUF(b) (smem + (b)*8192)
#define B1S_BUF(b) (smem + 16384 + (b)*4096)
#define B3S_BUF(b) (smem + 24576 + (b)*4096)
  float* comb = (float*)(smem + 32768);
  const int tid = threadIdx.x;
  const int id = blockIdx.x;
  const int mb = (id & 7) + ((id >> 7) << 3);
  const int f0 = ((id >> 3) & 15) * 64;
  const int e = sched_e[mb];
  if (e < 0) return;
  const int m0 = mb * 128;
  const int lane = tid & 63;
  const int wv = tid >> 6;
  const int wr = wv >> 1, wc = wv & 1;
  const int l15 = lane & 15, lhi = lane >> 4;
  const int ko = (lhi ^ ((l15 >> 1) & 3)) << 4;

  if (tid < 128) comb[tid] = pair_w[m0 + tid];

  size_t aoff[2];
  int lbA[2];
#pragma unroll
  for (int it = 0; it < 2; ++it) {
    const int chunk = it * 256 + tid;
    const int r = chunk >> 2;
    const int c8 = ((chunk & 3) ^ ((r >> 1) & 3)) * 8;
    aoff[it] = (size_t)pair_t[m0 + r] * DMODEL + c8;
    lbA[it] = (it * 256 + (tid & ~63)) * 16;
  }
  size_t boff;
  int lbB;
  {
    const int r = tid >> 2;
    const int c8 = ((tid & 3) ^ ((r >> 1) & 3)) * 8;
    boff = (size_t)(e * FFN + f0 + r) * DMODEL + c8;
    lbB = (tid & ~63) * 16;
  }

  const f32x4 fz = {0.f, 0.f, 0.f, 0.f};
  f32x4 acc1[4][2], acc3[4][2];
#pragma unroll
  for (int m = 0; m < 4; ++m)
#pragma unroll
    for (int n = 0; n < 2; ++n) { acc1[m][n] = fz; acc3[m][n] = fz; }

#define G1_STAGE(BUF, K0)                                                     \
  do {                                                                        \
    _Pragma("unroll") for (int it = 0; it < 2; ++it)                          \
        gload_lds16(xb + aoff[it] + (K0), AS_BUF(BUF) + lbA[it]);             \
    gload_lds16(w1t + boff + (K0), B1S_BUF(BUF) + lbB);                       \
    gload_lds16(w3t + boff + (K0), B3S_BUF(BUF) + lbB);                       \
  } while (0)

#define G1_COMPUTE(BUF)                                                       \
  do {                                                                        \
    __builtin_amdgcn_s_setprio(1);                                            \
    bf16x8 af[4], b1f[2], b3f[2];                                             \
    _Pragma("unroll") for (int m = 0; m < 4; ++m)                             \
        af[m] = *(const bf16x8*)(AS_BUF(BUF) +                                \
                                 (wr * 64 + m * 16 + l15) * 64 + ko);         \
    _Pragma("unroll") for (int n = 0; n < 2; ++n) {                           \
      const int ro = (wc * 32 + n * 16 + l15) * 64 + ko;                      \
      b1f[n] = *(const bf16x8*)(B1S_BUF(BUF) + ro);                           \
      b3f[n] = *(const bf16x8*)(B3S_BUF(BUF) + ro);                           \
    }                                                                         \
    _Pragma("unroll") for (int m = 0; m < 4; ++m)                             \
        _Pragma("unroll") for (int n = 0; n < 2; ++n) {                       \
      acc1[m][n] = __builtin_amdgcn_mfma_f32_16x16x32_bf16(af[m], b1f[n],     \
                                                           acc1[m][n], 0, 0, 0); \
      acc3[m][n] = __builtin_amdgcn_mfma_f32_16x16x32_bf16(af[m], b3f[n],     \
                                                           acc3[m][n], 0, 0, 0); \
    }                                                                         \
    __builtin_amdgcn_s_setprio(0);                                            \
  } while (0)

  G1_STAGE(0, 0);
#pragma unroll
  for (int t = 0; t < 15; ++t) {
    G1_STAGE((t + 1) & 1, (t + 1) * 32);
    PIPE_BAR_4();
    G1_COMPUTE(t & 1);
    POST_BAR();
  }
  PIPE_BAR_0();
  G1_COMPUTE(1);

  __syncthreads();
  {
    __bf16* eps = (__bf16*)smem;
    constexpr int EW = 72;
#pragma unroll
    for (int m = 0; m < 4; ++m)
#pragma unroll
      for (int n = 0; n < 2; ++n)
#pragma unroll
        for (int r = 0; r < 4; ++r) {
          const int row = wr * 64 + m * 16 + lhi * 4 + r;
          const int col = wc * 32 + n * 16 + l15;
          const float g = acc1[m][n][r];
          const float u = acc3[m][n][r];
          eps[row * EW + col] = (__bf16)((g / (1.f + __expf(-g))) * u * comb[row]);
        }
    __syncthreads();
#pragma unroll
    for (int p = 0; p < 4; ++p) {
      const int i = p * 256 + tid;
      const int row = i >> 3, c8 = (i & 7) * 8;
      *(bf16x8*)&hbuf[(size_t)(m0 + row) * FFN + f0 + c8] =
          *(const bf16x8*)&eps[row * EW + c8];
    }
  }
#undef G1_STAGE
#undef G1_COMPUTE
#undef AS_BUF
#undef B1S_BUF
#undef B3S_BUF
}

// ---------------- GEMM2 sparse: 128x64, BK=32, split-K=2, counted-vmcnt (R12) ----------------
__global__ __launch_bounds__(256) void gemm2_kernel(
    const __bf16* __restrict__ hbuf, const __bf16* __restrict__ w2t,
    const int* __restrict__ sched_e, __bf16* __restrict__ outp) {
  __shared__ alignas(16) char smem[24576];
#define AS_BUF(b) (smem + (b)*8192)
#define BS_BUF(b) (smem + 16384 + (b)*4096)
  const int tid = threadIdx.x;
  const int id = blockIdx.x;
  const int gk = (id & 7) + ((id >> 6) << 3);
  const int n0 = ((id >> 3) & 7) * 64;
  const int mb = gk >> 1;
  const int kz = gk & 1;
  const int e = sched_e[mb];
  if (e < 0) return;
  const int m0 = mb * 128;
  const int fbase = kz * (FFN / 2);
  const int lane = tid & 63;
  const int wv = tid >> 6;
  const int wr = wv >> 1, wc = wv & 1;
  const int l15 = lane & 15, lhi = lane >> 4;
  const int ko = (lhi ^ ((l15 >> 1) & 3)) << 4;

  size_t aoff[2];
  int lbA[2];
#pragma unroll
  for (int it = 0; it < 2; ++it) {
    const int chunk = it * 256 + tid;
    const int r = chunk >> 2;
    const int c8 = ((chunk & 3) ^ ((r >> 1) & 3)) * 8;
    aoff[it] = (size_t)(m0 + r) * FFN + fbase + c8;
    lbA[it] = (it * 256 + (tid & ~63)) * 16;
  }
  size_t boff;
  int lbB;
  {
    const int r = tid >> 2;
    const int c8 = ((tid & 3) ^ ((r >> 1) & 3)) * 8;
    boff = ((size_t)e * DMODEL + n0 + r) * FFN + fbase + c8;
    lbB = (tid & ~63) * 16;
  }

  const f32x4 fz = {0.f, 0.f, 0.f, 0.f};
  f32x4 acc[4][2];
#pragma unroll
  for (int m = 0; m < 4; ++m) { acc[m][0] = fz; acc[m][1] = fz; }

#define G2_STAGE(BUF, K0)                                                     \
  do {                                                                        \
    _Pragma("unroll") for (int it = 0; it < 2; ++it)                          \
        gload_lds16(hbuf + aoff[it] + (K0), AS_BUF(BUF) + lbA[it]);           \
    gload_lds16(w2t + boff + (K0), BS_BUF(BUF) + lbB);                        \
  } while (0)

#define G2_COMPUTE(BUF)                                                       \
  do {                                                                        \
    __builtin_amdgcn_s_setprio(1);                                            \
    bf16x8 af[4], bfr[2];                                                     \
    _Pragma("unroll") for (int m = 0; m < 4; ++m)                             \
        af[m] = *(const bf16x8*)(AS_BUF(BUF) +                                \
                                 (wr * 64 + m * 16 + l15) * 64 + ko);         \
    _Pragma("unroll") for (int n = 0; n < 2; ++n)                             \
        bfr[n] = *(const bf16x8*)(BS_BUF(BUF) +                               \
                                  (wc * 32 + n * 16 + l15) * 64 + ko);        \
    _Pragma("unroll") for (int m = 0; m < 4; ++m)                             \
        _Pragma("unroll") for (int n = 0; n < 2; ++n)                         \
            acc[m][n] = __builtin_amdgcn_mfma_f32_16x16x32_bf16(              \
                af[m], bfr[n], acc[m][n], 0, 0, 0);                           \
    __builtin_amdgcn_s_setprio(0);                                            \
  } while (0)

  G2_STAGE(0, 0);
#pragma unroll
  for (int t = 0; t < 15; ++t) {
    G2_STAGE((t + 1) & 1, (t + 1) * 32);
    PIPE_BAR_3();
    G2_COMPUTE(t & 1);
    POST_BAR();
  }
  PIPE_BAR_0();
  G2_COMPUTE(1);

  __syncthreads();
  {
    __bf16* eps = (__bf16*)smem;
    constexpr int EW = 72;
#pragma unroll
    for (int m = 0; m < 4; ++m)
#pragma unroll
      for (int n = 0; n < 2; ++n)
#pragma unroll
        for (int r = 0; r < 4; ++r) {
          const int row = wr * 64 + m * 16 + lhi * 4 + r;
          const int col = wc * 32 + n * 16 + l15;
          eps[row * EW + col] = (__bf16)acc[m][n][r];
        }
    __syncthreads();
#pragma unroll
    for (int p = 0; p < 4; ++p) {
      const int i = p * 256 + tid;
      const int row = i >> 3, c8 = (i & 7) * 8;
      *(bf16x8*)&outp[((size_t)kz * PCAP + m0 + row) * DMODEL + n0 + c8] =
          *(const bf16x8*)&eps[row * EW + c8];
    }
  }
#undef G2_STAGE
#undef G2_COMPUTE
#undef AS_BUF
#undef BS_BUF
}

// ---------------- gather: out[t] = sum of 2 pairs x 2 kz ----------------
__global__ __launch_bounds__(256) void gather_kernel(
    const __bf16* __restrict__ outp, const int* __restrict__ pairidx,
    float* __restrict__ out) {
  const int i = blockIdx.x * 256 + threadIdx.x;
  const int t = i >> 6;
  const int c = (i & 63) * 8;
  const int p0 = pairidx[t * 2];
  const int p1 = pairidx[t * 2 + 1];
  const size_t KZ = (size_t)PCAP * DMODEL;
  const bf16x8 a0 = *(const bf16x8*)&outp[(size_t)p0 * DMODEL + c];
  const bf16x8 a1 = *(const bf16x8*)&outp[(size_t)p1 * DMODEL + c];
  const bf16x8 b0 = *(const bf16x8*)&outp[KZ + (size_t)p0 * DMODEL + c];
  const bf16x8 b1 = *(const bf16x8*)&outp[KZ + (size_t)p1 * DMODEL + c];
  f32x4 lo, hi;
#pragma unroll
  for (int j = 0; j < 4; ++j)
    lo[j] = (float)a0[j] + (float)a1[j] + (float)b0[j] + (float)b1[j];
#pragma unroll
  for (int j = 0; j < 4; ++j)
    hi[j] = (float)a0[j + 4] + (float)a1[j + 4] + (float)b0[j + 4] + (float)b1[j + 4];
  float* op = out + (size_t)t * DMODEL + c;
  *(f32x4*)op = lo;
  *(f32x4*)(op + 4) = hi;
}

extern "C" void kernel_launch(void* const* d_in, const int* in_sizes, int n_in,
                              void* d_out, int out_size, void* d_ws, size_t ws_size,
                              hipStream_t stream) {
  const float* x = (const float*)d_in[0];
  const float* rw = (const float*)d_in[1];
  const float* w1 = (const float*)d_in[2];
  const float* w2 = (const float*)d_in[3];
  const float* w3 = (const float*)d_in[4];
  float* out = (float*)d_out;
  char* ws = (char*)d_ws;

  int* tope = (int*)(ws + 0);                  //    16,384
  float* topw = (float*)(ws + 16384);          //    16,384
  int* pair_t = (int*)(ws + 32768);            //    20,480
  float* pair_w = (float*)(ws + 53248);        //    20,480
  int* pairidx = (int*)(ws + 73728);           //    16,384
  int* sched_e = (int*)(ws + 90112);           //     8,192 (padded)
  __bf16* xb = (__bf16*)(ws + 98304);          // 2,097,152
  __bf16* w1t = (__bf16*)(ws + 2195456);       // 8,388,608  [E][F][D]
  __bf16* w3t = (__bf16*)(ws + 10584064);      // 8,388,608  [E][F][D]
  __bf16* w2t = (__bf16*)(ws + 18972672);      // 8,388,608  [E][D][F]
  __bf16* hbuf = (__bf16*)(ws + 27361280);     // 10,485,760 [PCAP][F]
  __bf16* outp = (__bf16*)(ws + 37847040);     // 10,485,760 [2][PCAP][D] bf16

  hipLaunchKernelGGL(prep_kernel, dim3(2568), dim3(256), 0, stream,
                     x, rw, w1, w3, xb, w1t, w3t, tope, topw,
                     pair_t, pair_w, sched_e);
  hipLaunchKernelGGL(build_w2t_kernel, dim3(1025), dim3(256), 0, stream,
                     w2, w2t, tope, topw, pair_t, pair_w, pairidx, sched_e);
  hipLaunchKernelGGL(gemm1_kernel, dim3(640), dim3(256), 0, stream,
                     xb, w1t, w3t, pair_t, pair_w, sched_e, hbuf);
  hipLaunchKernelGGL(gemm2_kernel, dim3(640), dim3(256), 0, stream,
                     hbuf, w2t, sched_e, outp);
  hipLaunchKernelGGL(gather_kernel, dim3(512), dim3(256), 0, stream,
                     outp, pairidx, out);
}

// Round 14
// 67.124 us; speedup vs baseline: 1.2883x; 1.0335x over previous
//
#include <hip/hip_runtime.h>
#include <hip/hip_bf16.h>

// MoE forward, top-2 sparse gather-GEMM.
// T=2048, D=512, F=1024, E=8, top-2. fp32 in/out, bf16 MFMA internally.
//
// Round 14 = R13 (69.4us) + ONE scheduling change: w2 transpose co-launched
// WITH gemm1 (blocks 0..639 = gemm1 tiles, 640..1663 = w2t tiles reusing the
// same smem buffer) so its 54MB of traffic hides under gemm1's latency-bound
// execution; build returns to a standalone 1-block launch.
// GEMM math paths byte-identical to R12/R13 (BK=32, counted-vmcnt, swizzle).

typedef __attribute__((ext_vector_type(4))) float f32x4;
typedef __attribute__((ext_vector_type(8))) __bf16 bf16x8;

#define T_TOK 2048
#define DMODEL 512
#define FFN 1024
#define NE 8
#define MAXMB 40
#define PCAP (MAXMB * 128)

__device__ __forceinline__ void gload_lds16(const void* g, void* l) {
  __builtin_amdgcn_global_load_lds(
      (const __attribute__((address_space(1))) void*)g,
      (__attribute__((address_space(3))) void*)l, 16, 0, 0);
}

#define PIPE_BAR_4()                                        \
  asm volatile("s_waitcnt vmcnt(4)" ::: "memory");          \
  __builtin_amdgcn_s_barrier();                             \
  __builtin_amdgcn_sched_barrier(0)
#define PIPE_BAR_3()                                        \
  asm volatile("s_waitcnt vmcnt(3)" ::: "memory");          \
  __builtin_amdgcn_s_barrier();                             \
  __builtin_amdgcn_sched_barrier(0)
#define PIPE_BAR_0()                                        \
  asm volatile("s_waitcnt vmcnt(0)" ::: "memory");          \
  __builtin_amdgcn_s_barrier();                             \
  __builtin_amdgcn_sched_barrier(0)
#define POST_BAR()                                          \
  __builtin_amdgcn_s_barrier();                             \
  __builtin_amdgcn_sched_barrier(0)

// ---------------- prep: w1/w3 transposes + cvt_router + inits ----------------
__global__ __launch_bounds__(256) void prep_kernel(
    const float* __restrict__ x, const float* __restrict__ rw,
    const float* __restrict__ w1, const float* __restrict__ w3,
    __bf16* __restrict__ xb, __bf16* __restrict__ w1t,
    __bf16* __restrict__ w3t, int* __restrict__ tope, float* __restrict__ topw,
    int* __restrict__ pair_t, float* __restrict__ pair_w,
    int* __restrict__ sched_e) {
  const int bx = blockIdx.x;
  const int tid = threadIdx.x;

  if (bx < 2048) {
    __shared__ __bf16 tile[64][65];
    const float* src;
    __bf16* dst;
    int idx;
    if (bx < 1024) { src = w1; dst = w1t; idx = bx; }
    else           { src = w3; dst = w3t; idx = bx - 1024; }
    const int R = 512, C = 1024;
    const int ntx = C >> 6, nty = R >> 6;
    const int cx = idx % ntx;
    const int gry = idx / ntx;
    const int e = gry / nty;
    const int r0 = (gry % nty) * 64;
    const int c0 = cx * 64;
    src += (size_t)e * R * C;
    dst += (size_t)e * R * C;
#pragma unroll
    for (int q = 0; q < 4; ++q) {
      const int r = (tid >> 4) + q * 16;
      const int c = (tid & 15) * 4;
      const f32x4 v = *(const f32x4*)&src[(size_t)(r0 + r) * C + c0 + c];
      tile[r][c] = (__bf16)v[0];
      tile[r][c + 1] = (__bf16)v[1];
      tile[r][c + 2] = (__bf16)v[2];
      tile[r][c + 3] = (__bf16)v[3];
    }
    __syncthreads();
#pragma unroll
    for (int p = 0; p < 2; ++p) {
      const int cc = (tid >> 3) + p * 32;
      const int rr = (tid & 7) * 8;
      union { bf16x8 v; __bf16 s[8]; } u;
#pragma unroll
      for (int i = 0; i < 8; ++i) u.s[i] = tile[rr + i][cc];
      *(bf16x8*)&dst[(size_t)(c0 + cc) * R + r0 + rr] = u.v;
    }
  } else if (bx < 2560) {
    // ---- x -> bf16 + router top-2 ----
    const int t = (bx - 2048) * 4 + (tid >> 6);
    const int lane = tid & 63;
    const float* xr = x + (size_t)t * DMODEL + lane * 8;
    const f32x4 a = *(const f32x4*)xr;
    const f32x4 b = *(const f32x4*)(xr + 4);
    bf16x8 v;
    v[0] = (__bf16)a[0]; v[1] = (__bf16)a[1]; v[2] = (__bf16)a[2]; v[3] = (__bf16)a[3];
    v[4] = (__bf16)b[0]; v[5] = (__bf16)b[1]; v[6] = (__bf16)b[2]; v[7] = (__bf16)b[3];
    *(bf16x8*)&xb[(size_t)t * DMODEL + lane * 8] = v;

    float xv[8] = {a[0], a[1], a[2], a[3], b[0], b[1], b[2], b[3]};
    float part[NE];
#pragma unroll
    for (int e = 0; e < NE; ++e) part[e] = 0.f;
#pragma unroll
    for (int i = 0; i < 8; ++i) {
      const int d = lane * 8 + i;
      const f32x4 r0 = *(const f32x4*)&rw[(size_t)d * NE];
      const f32x4 r1 = *(const f32x4*)&rw[(size_t)d * NE + 4];
      part[0] += xv[i] * r0[0]; part[1] += xv[i] * r0[1];
      part[2] += xv[i] * r0[2]; part[3] += xv[i] * r0[3];
      part[4] += xv[i] * r1[0]; part[5] += xv[i] * r1[1];
      part[6] += xv[i] * r1[2]; part[7] += xv[i] * r1[3];
    }
#pragma unroll
    for (int off = 32; off > 0; off >>= 1) {
#pragma unroll
      for (int e = 0; e < NE; ++e) part[e] += __shfl_xor(part[e], off);
    }
    if (lane == 0) {
      int ia = 0;
#pragma unroll
      for (int e = 1; e < NE; ++e)
        if (part[e] > part[ia]) ia = e;
      int ib = (ia == 0) ? 1 : 0;
#pragma unroll
      for (int e = 0; e < NE; ++e)
        if (e != ia && e != ib && part[e] > part[ib]) ib = e;
      const float wa = 1.f / (1.f + __expf(part[ib] - part[ia]));
      tope[t * 2] = ia;
      tope[t * 2 + 1] = ib;
      topw[t * 2] = wa;
      topw[t * 2 + 1] = 1.f - wa;
    }
  } else {
    const int i = (bx - 2560) * 256 + tid;
    for (int j = i; j < PCAP; j += 2048) { pair_t[j] = 0; pair_w[j] = 0.f; }
    if (i < MAXMB) sched_e[i] = -1;
  }
}

// ---------------- build: count + schedule + scatter (simple-atomic) ----------------
__global__ __launch_bounds__(256) void build_kernel(
    const int* __restrict__ tope, const float* __restrict__ topw,
    int* __restrict__ pair_t, float* __restrict__ pair_w,
    int* __restrict__ pairidx, int* __restrict__ sched_e) {
  __shared__ int cnt[NE], base[NE], ofs[NE];
  const int tid = threadIdx.x;
  if (tid < NE) { cnt[tid] = 0; ofs[tid] = 0; }
  __syncthreads();
  for (int t = tid; t < T_TOK; t += 256) {
    atomicAdd(&cnt[tope[t * 2]], 1);
    atomicAdd(&cnt[tope[t * 2 + 1]], 1);
  }
  __syncthreads();
  if (tid == 0) {
    int mb = 0;
    for (int e = 0; e < NE; ++e) {
      base[e] = mb * 128;
      const int nmb = (cnt[e] + 127) >> 7;
      for (int i = 0; i < nmb; ++i) sched_e[mb + i] = e;
      mb += nmb;
    }
  }
  __syncthreads();
  for (int t = tid; t < T_TOK; t += 256) {
#pragma unroll
    for (int s = 0; s < 2; ++s) {
      const int e = tope[t * 2 + s];
      const int pos = base[e] + atomicAdd(&ofs[e], 1);
      pair_t[pos] = t;
      pair_w[pos] = topw[t * 2 + s];
      pairidx[t * 2 + s] = pos;
    }
  }
}

// ---------------- GEMM1 (blocks 0..639) + w2 transpose (blocks 640..1663) ----------------
// gemm1: 128(pairs) x 64(f), BK=32, counted-vmcnt, identical math to R12/R13.
// w2t blocks reuse smem as a [64][65] bf16 tile; they dispatch after gemm1
// fills the CUs and hide their 54MB traffic under gemm1's latency-bound run.
__global__ __launch_bounds__(256) void gemm1_kernel(
    const __bf16* __restrict__ xb, const __bf16* __restrict__ w1t,
    const __bf16* __restrict__ w3t, const float* __restrict__ w2,
    __bf16* __restrict__ w2t, const int* __restrict__ pair_t,
    const float* __restrict__ pair_w, const int* __restrict__ sched_e,
    __bf16* __restrict__ hbuf) {
  __shared__ alignas(16) char smem[33280];
  const int tid = threadIdx.x;
  const int id = blockIdx.x;

  if (id >= 640) {
    // ---- w2 transpose + cvt: w2[e][1024][512] f32 -> w2t[e][512][1024] bf16 ----
    __bf16(*tile)[65] = (__bf16(*)[65])smem;
    const int bx = id - 640;
    const int R = 1024, C = 512;
    const int ntx = C >> 6, nty = R >> 6;
    const int cx = bx % ntx;
    const int gry = bx / ntx;
    const int e = gry / nty;
    const int r0 = (gry % nty) * 64;
    const int c0 = cx * 64;
    const float* src = w2 + (size_t)e * R * C;
    __bf16* dst = w2t + (size_t)e * R * C;
#pragma unroll
    for (int q = 0; q < 4; ++q) {
      const int r = (tid >> 4) + q * 16;
      const int c = (tid & 15) * 4;
      const f32x4 v = *(const f32x4*)&src[(size_t)(r0 + r) * C + c0 + c];
      tile[r][c] = (__bf16)v[0];
      tile[r][c + 1] = (__bf16)v[1];
      tile[r][c + 2] = (__bf16)v[2];
      tile[r][c + 3] = (__bf16)v[3];
    }
    __syncthreads();
#pragma unroll
    for (int p = 0; p < 2; ++p) {
      const int cc = (tid >> 3) + p * 32;
      const int rr = (tid & 7) * 8;
      union { bf16x8 v; __bf16 s[8]; } u;
#pragma unroll
      for (int i = 0; i < 8; ++i) u.s[i] = tile[rr + i][cc];
      *(bf16x8*)&dst[(size_t)(c0 + cc) * R + r0 + rr] = u.v;
    }
    return;
  }

#define AS_BUF(b) (smem + (b)*8192)
#define B1S_BUF(b) (smem + 16384 + (b)*4096)
#define B3S_BUF(b) (smem + 24576 + (b)*4096)
  float* comb = (float*)(smem + 32768);
  const int mb = (id & 7) + ((id >> 7) << 3);
  const int f0 = ((id >> 3) & 15) * 64;
  const int e = sched_e[mb];
  if (e < 0) return;
  const int m0 = mb * 128;
  const int lane = tid & 63;
  const int wv = tid >> 6;
  const int wr = wv >> 1, wc = wv & 1;
  const int l15 = lane & 15, lhi = lane >> 4;
  const int ko = (lhi ^ ((l15 >> 1) & 3)) << 4;

  if (tid < 128) comb[tid] = pair_w[m0 + tid];

  size_t aoff[2];
  int lbA[2];
#pragma unroll
  for (int it = 0; it < 2; ++it) {
    const int chunk = it * 256 + tid;
    const int r = chunk >> 2;
    const int c8 = ((chunk & 3) ^ ((r >> 1) & 3)) * 8;
    aoff[it] = (size_t)pair_t[m0 + r] * DMODEL + c8;
    lbA[it] = (it * 256 + (tid & ~63)) * 16;
  }
  size_t boff;
  int lbB;
  {
    const int r = tid >> 2;
    const int c8 = ((tid & 3) ^ ((r >> 1) & 3)) * 8;
    boff = (size_t)(e * FFN + f0 + r) * DMODEL + c8;
    lbB = (tid & ~63) * 16;
  }

  const f32x4 fz = {0.f, 0.f, 0.f, 0.f};
  f32x4 acc1[4][2], acc3[4][2];
#pragma unroll
  for (int m = 0; m < 4; ++m)
#pragma unroll
    for (int n = 0; n < 2; ++n) { acc1[m][n] = fz; acc3[m][n] = fz; }

#define G1_STAGE(BUF, K0)                                                     \
  do {                                                                        \
    _Pragma("unroll") for (int it = 0; it < 2; ++it)                          \
        gload_lds16(xb + aoff[it] + (K0), AS_BUF(BUF) + lbA[it]);             \
    gload_lds16(w1t + boff + (K0), B1S_BUF(BUF) + lbB);                       \
    gload_lds16(w3t + boff + (K0), B3S_BUF(BUF) + lbB);                       \
  } while (0)

#define G1_COMPUTE(BUF)                                                       \
  do {                                                                        \
    __builtin_amdgcn_s_setprio(1);                                            \
    bf16x8 af[4], b1f[2], b3f[2];                                             \
    _Pragma("unroll") for (int m = 0; m < 4; ++m)                             \
        af[m] = *(const bf16x8*)(AS_BUF(BUF) +                                \
                                 (wr * 64 + m * 16 + l15) * 64 + ko);         \
    _Pragma("unroll") for (int n = 0; n < 2; ++n) {                           \
      const int ro = (wc * 32 + n * 16 + l15) * 64 + ko;                      \
      b1f[n] = *(const bf16x8*)(B1S_BUF(BUF) + ro);                           \
      b3f[n] = *(const bf16x8*)(B3S_BUF(BUF) + ro);                           \
    }                                                                         \
    _Pragma("unroll") for (int m = 0; m < 4; ++m)                             \
        _Pragma("unroll") for (int n = 0; n < 2; ++n) {                       \
      acc1[m][n] = __builtin_amdgcn_mfma_f32_16x16x32_bf16(af[m], b1f[n],     \
                                                           acc1[m][n], 0, 0, 0); \
      acc3[m][n] = __builtin_amdgcn_mfma_f32_16x16x32_bf16(af[m], b3f[n],     \
                                                           acc3[m][n], 0, 0, 0); \
    }                                                                         \
    __builtin_amdgcn_s_setprio(0);                                            \
  } while (0)

  G1_STAGE(0, 0);
#pragma unroll
  for (int t = 0; t < 15; ++t) {
    G1_STAGE((t + 1) & 1, (t + 1) * 32);
    PIPE_BAR_4();
    G1_COMPUTE(t & 1);
    POST_BAR();
  }
  PIPE_BAR_0();
  G1_COMPUTE(1);

  __syncthreads();
  {
    __bf16* eps = (__bf16*)smem;
    constexpr int EW = 72;
#pragma unroll
    for (int m = 0; m < 4; ++m)
#pragma unroll
      for (int n = 0; n < 2; ++n)
#pragma unroll
        for (int r = 0; r < 4; ++r) {
          const int row = wr * 64 + m * 16 + lhi * 4 + r;
          const int col = wc * 32 + n * 16 + l15;
          const float g = acc1[m][n][r];
          const float u = acc3[m][n][r];
          eps[row * EW + col] = (__bf16)((g / (1.f + __expf(-g))) * u * comb[row]);
        }
    __syncthreads();
#pragma unroll
    for (int p = 0; p < 4; ++p) {
      const int i = p * 256 + tid;
      const int row = i >> 3, c8 = (i & 7) * 8;
      *(bf16x8*)&hbuf[(size_t)(m0 + row) * FFN + f0 + c8] =
          *(const bf16x8*)&eps[row * EW + c8];
    }
  }
#undef G1_STAGE
#undef G1_COMPUTE
#undef AS_BUF
#undef B1S_BUF
#undef B3S_BUF
}

// ---------------- GEMM2 sparse: 128x64, BK=32, split-K=2, counted-vmcnt (R12) ----------------
__global__ __launch_bounds__(256) void gemm2_kernel(
    const __bf16* __restrict__ hbuf, const __bf16* __restrict__ w2t,
    const int* __restrict__ sched_e, __bf16* __restrict__ outp) {
  __shared__ alignas(16) char smem[24576];
#define AS_BUF(b) (smem + (b)*8192)
#define BS_BUF(b) (smem + 16384 + (b)*4096)
  const int tid = threadIdx.x;
  const int id = blockIdx.x;
  const int gk = (id & 7) + ((id >> 6) << 3);
  const int n0 = ((id >> 3) & 7) * 64;
  const int mb = gk >> 1;
  const int kz = gk & 1;
  const int e = sched_e[mb];
  if (e < 0) return;
  const int m0 = mb * 128;
  const int fbase = kz * (FFN / 2);
  const int lane = tid & 63;
  const int wv = tid >> 6;
  const int wr = wv >> 1, wc = wv & 1;
  const int l15 = lane & 15, lhi = lane >> 4;
  const int ko = (lhi ^ ((l15 >> 1) & 3)) << 4;

  size_t aoff[2];
  int lbA[2];
#pragma unroll
  for (int it = 0; it < 2; ++it) {
    const int chunk = it * 256 + tid;
    const int r = chunk >> 2;
    const int c8 = ((chunk & 3) ^ ((r >> 1) & 3)) * 8;
    aoff[it] = (size_t)(m0 + r) * FFN + fbase + c8;
    lbA[it] = (it * 256 + (tid & ~63)) * 16;
  }
  size_t boff;
  int lbB;
  {
    const int r = tid >> 2;
    const int c8 = ((tid & 3) ^ ((r >> 1) & 3)) * 8;
    boff = ((size_t)e * DMODEL + n0 + r) * FFN + fbase + c8;
    lbB = (tid & ~63) * 16;
  }

  const f32x4 fz = {0.f, 0.f, 0.f, 0.f};
  f32x4 acc[4][2];
#pragma unroll
  for (int m = 0; m < 4; ++m) { acc[m][0] = fz; acc[m][1] = fz; }

#define G2_STAGE(BUF, K0)                                                     \
  do {                                                                        \
    _Pragma("unroll") for (int it = 0; it < 2; ++it)                          \
        gload_lds16(hbuf + aoff[it] + (K0), AS_BUF(BUF) + lbA[it]);           \
    gload_lds16(w2t + boff + (K0), BS_BUF(BUF) + lbB);                        \
  } while (0)

#define G2_COMPUTE(BUF)                                                       \
  do {                                                                        \
    __builtin_amdgcn_s_setprio(1);                                            \
    bf16x8 af[4], bfr[2];                                                     \
    _Pragma("unroll") for (int m = 0; m < 4; ++m)                             \
        af[m] = *(const bf16x8*)(AS_BUF(BUF) +                                \
                                 (wr * 64 + m * 16 + l15) * 64 + ko);         \
    _Pragma("unroll") for (int n = 0; n < 2; ++n)                             \
        bfr[n] = *(const bf16x8*)(BS_BUF(BUF) +                               \
                                  (wc * 32 + n * 16 + l15) * 64 + ko);        \
    _Pragma("unroll") for (int m = 0; m < 4; ++m)                             \
        _Pragma("unroll") for (int n = 0; n < 2; ++n)                         \
            acc[m][n] = __builtin_amdgcn_mfma_f32_16x16x32_bf16(              \
                af[m], bfr[n], acc[m][n], 0, 0, 0);                           \
    __builtin_amdgcn_s_setprio(0);                                            \
  } while (0)

  G2_STAGE(0, 0);
#pragma unroll
  for (int t = 0; t < 15; ++t) {
    G2_STAGE((t + 1) & 1, (t + 1) * 32);
    PIPE_BAR_3();
    G2_COMPUTE(t & 1);
    POST_BAR();
  }
  PIPE_BAR_0();
  G2_COMPUTE(1);

  __syncthreads();
  {
    __bf16* eps = (__bf16*)smem;
    constexpr int EW = 72;
#pragma unroll
    for (int m = 0; m < 4; ++m)
#pragma unroll
      for (int n = 0; n < 2; ++n)
#pragma unroll
        for (int r = 0; r < 4; ++r) {
          const int row = wr * 64 + m * 16 + lhi * 4 + r;
          const int col = wc * 32 + n * 16 + l15;
          eps[row * EW + col] = (__bf16)acc[m][n][r];
        }
    __syncthreads();
#pragma unroll
    for (int p = 0; p < 4; ++p) {
      const int i = p * 256 + tid;
      const int row = i >> 3, c8 = (i & 7) * 8;
      *(bf16x8*)&outp[((size_t)kz * PCAP + m0 + row) * DMODEL + n0 + c8] =
          *(const bf16x8*)&eps[row * EW + c8];
    }
  }
#undef G2_STAGE
#undef G2_COMPUTE
#undef AS_BUF
#undef BS_BUF
}

// ---------------- gather: out[t] = sum of 2 pairs x 2 kz ----------------
__global__ __launch_bounds__(256) void gather_kernel(
    const __bf16* __restrict__ outp, const int* __restrict__ pairidx,
    float* __restrict__ out) {
  const int i = blockIdx.x * 256 + threadIdx.x;
  const int t = i >> 6;
  const int c = (i & 63) * 8;
  const int p0 = pairidx[t * 2];
  const int p1 = pairidx[t * 2 + 1];
  const size_t KZ = (size_t)PCAP * DMODEL;
  const bf16x8 a0 = *(const bf16x8*)&outp[(size_t)p0 * DMODEL + c];
  const bf16x8 a1 = *(const bf16x8*)&outp[(size_t)p1 * DMODEL + c];
  const bf16x8 b0 = *(const bf16x8*)&outp[KZ + (size_t)p0 * DMODEL + c];
  const bf16x8 b1 = *(const bf16x8*)&outp[KZ + (size_t)p1 * DMODEL + c];
  f32x4 lo, hi;
#pragma unroll
  for (int j = 0; j < 4; ++j)
    lo[j] = (float)a0[j] + (float)a1[j] + (float)b0[j] + (float)b1[j];
#pragma unroll
  for (int j = 0; j < 4; ++j)
    hi[j] = (float)a0[j + 4] + (float)a1[j + 4] + (float)b0[j + 4] + (float)b1[j + 4];
  float* op = out + (size_t)t * DMODEL + c;
  *(f32x4*)op = lo;
  *(f32x4*)(op + 4) = hi;
}

extern "C" void kernel_launch(void* const* d_in, const int* in_sizes, int n_in,
                              void* d_out, int out_size, void* d_ws, size_t ws_size,
                              hipStream_t stream) {
  const float* x = (const float*)d_in[0];
  const float* rw = (const float*)d_in[1];
  const float* w1 = (const float*)d_in[2];
  const float* w2 = (const float*)d_in[3];
  const float* w3 = (const float*)d_in[4];
  float* out = (float*)d_out;
  char* ws = (char*)d_ws;

  int* tope = (int*)(ws + 0);                  //    16,384
  float* topw = (float*)(ws + 16384);          //    16,384
  int* pair_t = (int*)(ws + 32768);            //    20,480
  float* pair_w = (float*)(ws + 53248);        //    20,480
  int* pairidx = (int*)(ws + 73728);           //    16,384
  int* sched_e = (int*)(ws + 90112);           //     8,192 (padded)
  __bf16* xb = (__bf16*)(ws + 98304);          // 2,097,152
  __bf16* w1t = (__bf16*)(ws + 2195456);       // 8,388,608  [E][F][D]
  __bf16* w3t = (__bf16*)(ws + 10584064);      // 8,388,608  [E][F][D]
  __bf16* w2t = (__bf16*)(ws + 18972672);      // 8,388,608  [E][D][F]
  __bf16* hbuf = (__bf16*)(ws + 27361280);     // 10,485,760 [PCAP][F]
  __bf16* outp = (__bf16*)(ws + 37847040);     // 10,485,760 [2][PCAP][D] bf16

  hipLaunchKernelGGL(prep_kernel, dim3(2568), dim3(256), 0, stream,
                     x, rw, w1, w3, xb, w1t, w3t, tope, topw,
                     pair_t, pair_w, sched_e);
  hipLaunchKernelGGL(build_kernel, dim3(1), dim3(256), 0, stream,
                     tope, topw, pair_t, pair_w, pairidx, sched_e);
  hipLaunchKernelGGL(gemm1_kernel, dim3(640 + 1024), dim3(256), 0, stream,
                     xb, w1t, w3t, w2, w2t, pair_t, pair_w, sched_e, hbuf);
  hipLaunchKernelGGL(gemm2_kernel, dim3(640), dim3(256), 0, stream,
                     hbuf, w2t, sched_e, outp);
  hipLaunchKernelGGL(gather_kernel, dim3(512), dim3(256), 0, stream,
                     outp, pairidx, out);
}

// Round 15
// 66.722 us; speedup vs baseline: 1.2961x; 1.0060x over previous
//
#include <hip/hip_runtime.h>
#include <hip/hip_bf16.h>

// MoE forward, top-2 sparse gather-GEMM.
// T=2048, D=512, F=1024, E=8, top-2. fp32 in/out, bf16 MFMA internally.
//
// Round 15 = R14 (67.1us) + ONE scheduling change: split prep so build hides
// under the w1/w3 transposes.
//   k1 router: x->bf16 + top-2 + pair/sched init (520 blocks, ~2.5us)
//   k2 trans13+build: w1/w3 transpose tiles (0..2047) co-launched with the
//      1-block build (block 2048) -> build hides under BW-bound transposes
//   k3 gemm1 (0..639) + w2 transpose (640..1663)   [R14, unchanged]
//   k4 gemm2, k5 gather                             [R12, unchanged]

typedef __attribute__((ext_vector_type(4))) float f32x4;
typedef __attribute__((ext_vector_type(8))) __bf16 bf16x8;

#define T_TOK 2048
#define DMODEL 512
#define FFN 1024
#define NE 8
#define MAXMB 40
#define PCAP (MAXMB * 128)

__device__ __forceinline__ void gload_lds16(const void* g, void* l) {
  __builtin_amdgcn_global_load_lds(
      (const __attribute__((address_space(1))) void*)g,
      (__attribute__((address_space(3))) void*)l, 16, 0, 0);
}

#define PIPE_BAR_4()                                        \
  asm volatile("s_waitcnt vmcnt(4)" ::: "memory");          \
  __builtin_amdgcn_s_barrier();                             \
  __builtin_amdgcn_sched_barrier(0)
#define PIPE_BAR_3()                                        \
  asm volatile("s_waitcnt vmcnt(3)" ::: "memory");          \
  __builtin_amdgcn_s_barrier();                             \
  __builtin_amdgcn_sched_barrier(0)
#define PIPE_BAR_0()                                        \
  asm volatile("s_waitcnt vmcnt(0)" ::: "memory");          \
  __builtin_amdgcn_s_barrier();                             \
  __builtin_amdgcn_sched_barrier(0)
#define POST_BAR()                                          \
  __builtin_amdgcn_s_barrier();                             \
  __builtin_amdgcn_sched_barrier(0)

// ---------------- k1: router (x->bf16 + top-2) + inits ----------------
__global__ __launch_bounds__(256) void router_kernel(
    const float* __restrict__ x, const float* __restrict__ rw,
    __bf16* __restrict__ xb, int* __restrict__ tope, float* __restrict__ topw,
    int* __restrict__ pair_t, float* __restrict__ pair_w,
    int* __restrict__ sched_e) {
  const int bx = blockIdx.x;
  const int tid = threadIdx.x;
  if (bx < 512) {
    const int t = bx * 4 + (tid >> 6);
    const int lane = tid & 63;
    const float* xr = x + (size_t)t * DMODEL + lane * 8;
    const f32x4 a = *(const f32x4*)xr;
    const f32x4 b = *(const f32x4*)(xr + 4);
    bf16x8 v;
    v[0] = (__bf16)a[0]; v[1] = (__bf16)a[1]; v[2] = (__bf16)a[2]; v[3] = (__bf16)a[3];
    v[4] = (__bf16)b[0]; v[5] = (__bf16)b[1]; v[6] = (__bf16)b[2]; v[7] = (__bf16)b[3];
    *(bf16x8*)&xb[(size_t)t * DMODEL + lane * 8] = v;

    float xv[8] = {a[0], a[1], a[2], a[3], b[0], b[1], b[2], b[3]};
    float part[NE];
#pragma unroll
    for (int e = 0; e < NE; ++e) part[e] = 0.f;
#pragma unroll
    for (int i = 0; i < 8; ++i) {
      const int d = lane * 8 + i;
      const f32x4 r0 = *(const f32x4*)&rw[(size_t)d * NE];
      const f32x4 r1 = *(const f32x4*)&rw[(size_t)d * NE + 4];
      part[0] += xv[i] * r0[0]; part[1] += xv[i] * r0[1];
      part[2] += xv[i] * r0[2]; part[3] += xv[i] * r0[3];
      part[4] += xv[i] * r1[0]; part[5] += xv[i] * r1[1];
      part[6] += xv[i] * r1[2]; part[7] += xv[i] * r1[3];
    }
#pragma unroll
    for (int off = 32; off > 0; off >>= 1) {
#pragma unroll
      for (int e = 0; e < NE; ++e) part[e] += __shfl_xor(part[e], off);
    }
    if (lane == 0) {
      int ia = 0;
#pragma unroll
      for (int e = 1; e < NE; ++e)
        if (part[e] > part[ia]) ia = e;
      int ib = (ia == 0) ? 1 : 0;
#pragma unroll
      for (int e = 0; e < NE; ++e)
        if (e != ia && e != ib && part[e] > part[ib]) ib = e;
      const float wa = 1.f / (1.f + __expf(part[ib] - part[ia]));
      tope[t * 2] = ia;
      tope[t * 2 + 1] = ib;
      topw[t * 2] = wa;
      topw[t * 2 + 1] = 1.f - wa;
    }
  } else {
    // ---- init pair lists (padding rows = token 0, weight 0) + schedule ----
    const int i = (bx - 512) * 256 + tid;  // 0..2047
    for (int j = i; j < PCAP; j += 2048) { pair_t[j] = 0; pair_w[j] = 0.f; }
    if (i < MAXMB) sched_e[i] = -1;
  }
}

// ---------------- k2: w1/w3 transposes (0..2047) + build (block 2048) ----------------
__global__ __launch_bounds__(256) void trans13_build_kernel(
    const float* __restrict__ w1, const float* __restrict__ w3,
    __bf16* __restrict__ w1t, __bf16* __restrict__ w3t,
    const int* __restrict__ tope, const float* __restrict__ topw,
    int* __restrict__ pair_t, float* __restrict__ pair_w,
    int* __restrict__ pairidx, int* __restrict__ sched_e) {
  const int bx = blockIdx.x;
  const int tid = threadIdx.x;
  if (bx < 2048) {
    __shared__ __bf16 tile[64][65];
    const float* src;
    __bf16* dst;
    int idx;
    if (bx < 1024) { src = w1; dst = w1t; idx = bx; }
    else           { src = w3; dst = w3t; idx = bx - 1024; }
    const int R = 512, C = 1024;
    const int ntx = C >> 6, nty = R >> 6;
    const int cx = idx % ntx;
    const int gry = idx / ntx;
    const int e = gry / nty;
    const int r0 = (gry % nty) * 64;
    const int c0 = cx * 64;
    src += (size_t)e * R * C;
    dst += (size_t)e * R * C;
#pragma unroll
    for (int q = 0; q < 4; ++q) {
      const int r = (tid >> 4) + q * 16;
      const int c = (tid & 15) * 4;
      const f32x4 v = *(const f32x4*)&src[(size_t)(r0 + r) * C + c0 + c];
      tile[r][c] = (__bf16)v[0];
      tile[r][c + 1] = (__bf16)v[1];
      tile[r][c + 2] = (__bf16)v[2];
      tile[r][c + 3] = (__bf16)v[3];
    }
    __syncthreads();
#pragma unroll
    for (int p = 0; p < 2; ++p) {
      const int cc = (tid >> 3) + p * 32;
      const int rr = (tid & 7) * 8;
      union { bf16x8 v; __bf16 s[8]; } u;
#pragma unroll
      for (int i = 0; i < 8; ++i) u.s[i] = tile[rr + i][cc];
      *(bf16x8*)&dst[(size_t)(c0 + cc) * R + r0 + rr] = u.v;
    }
  } else {
    // ---- build: count + schedule + scatter (simple-atomic) ----
    __shared__ int cnt[NE], base[NE], ofs[NE];
    if (tid < NE) { cnt[tid] = 0; ofs[tid] = 0; }
    __syncthreads();
    for (int t = tid; t < T_TOK; t += 256) {
      atomicAdd(&cnt[tope[t * 2]], 1);
      atomicAdd(&cnt[tope[t * 2 + 1]], 1);
    }
    __syncthreads();
    if (tid == 0) {
      int mb = 0;
      for (int e = 0; e < NE; ++e) {
        base[e] = mb * 128;
        const int nmb = (cnt[e] + 127) >> 7;
        for (int i = 0; i < nmb; ++i) sched_e[mb + i] = e;
        mb += nmb;
      }
    }
    __syncthreads();
    for (int t = tid; t < T_TOK; t += 256) {
#pragma unroll
      for (int s = 0; s < 2; ++s) {
        const int e = tope[t * 2 + s];
        const int pos = base[e] + atomicAdd(&ofs[e], 1);
        pair_t[pos] = t;
        pair_w[pos] = topw[t * 2 + s];
        pairidx[t * 2 + s] = pos;
      }
    }
  }
}

// ---------------- k3: GEMM1 (blocks 0..639) + w2 transpose (640..1663) ----------------
__global__ __launch_bounds__(256) void gemm1_kernel(
    const __bf16* __restrict__ xb, const __bf16* __restrict__ w1t,
    const __bf16* __restrict__ w3t, const float* __restrict__ w2,
    __bf16* __restrict__ w2t, const int* __restrict__ pair_t,
    const float* __restrict__ pair_w, const int* __restrict__ sched_e,
    __bf16* __restrict__ hbuf) {
  __shared__ alignas(16) char smem[33280];
  const int tid = threadIdx.x;
  const int id = blockIdx.x;

  if (id >= 640) {
    // ---- w2 transpose + cvt: w2[e][1024][512] f32 -> w2t[e][512][1024] bf16 ----
    __bf16(*tile)[65] = (__bf16(*)[65])smem;
    const int bx = id - 640;
    const int R = 1024, C = 512;
    const int ntx = C >> 6, nty = R >> 6;
    const int cx = bx % ntx;
    const int gry = bx / ntx;
    const int e = gry / nty;
    const int r0 = (gry % nty) * 64;
    const int c0 = cx * 64;
    const float* src = w2 + (size_t)e * R * C;
    __bf16* dst = w2t + (size_t)e * R * C;
#pragma unroll
    for (int q = 0; q < 4; ++q) {
      const int r = (tid >> 4) + q * 16;
      const int c = (tid & 15) * 4;
      const f32x4 v = *(const f32x4*)&src[(size_t)(r0 + r) * C + c0 + c];
      tile[r][c] = (__bf16)v[0];
      tile[r][c + 1] = (__bf16)v[1];
      tile[r][c + 2] = (__bf16)v[2];
      tile[r][c + 3] = (__bf16)v[3];
    }
    __syncthreads();
#pragma unroll
    for (int p = 0; p < 2; ++p) {
      const int cc = (tid >> 3) + p * 32;
      const int rr = (tid & 7) * 8;
      union { bf16x8 v; __bf16 s[8]; } u;
#pragma unroll
      for (int i = 0; i < 8; ++i) u.s[i] = tile[rr + i][cc];
      *(bf16x8*)&dst[(size_t)(c0 + cc) * R + r0 + rr] = u.v;
    }
    return;
  }

#define AS_BUF(b) (smem + (b)*8192)
#define B1S_BUF(b) (smem + 16384 + (b)*4096)
#define B3S_BUF(b) (smem + 24576 + (b)*4096)
  float* comb = (float*)(smem + 32768);
  const int mb = (id & 7) + ((id >> 7) << 3);
  const int f0 = ((id >> 3) & 15) * 64;
  const int e = sched_e[mb];
  if (e < 0) return;
  const int m0 = mb * 128;
  const int lane = tid & 63;
  const int wv = tid >> 6;
  const int wr = wv >> 1, wc = wv & 1;
  const int l15 = lane & 15, lhi = lane >> 4;
  const int ko = (lhi ^ ((l15 >> 1) & 3)) << 4;

  if (tid < 128) comb[tid] = pair_w[m0 + tid];

  size_t aoff[2];
  int lbA[2];
#pragma unroll
  for (int it = 0; it < 2; ++it) {
    const int chunk = it * 256 + tid;
    const int r = chunk >> 2;
    const int c8 = ((chunk & 3) ^ ((r >> 1) & 3)) * 8;
    aoff[it] = (size_t)pair_t[m0 + r] * DMODEL + c8;
    lbA[it] = (it * 256 + (tid & ~63)) * 16;
  }
  size_t boff;
  int lbB;
  {
    const int r = tid >> 2;
    const int c8 = ((tid & 3) ^ ((r >> 1) & 3)) * 8;
    boff = (size_t)(e * FFN + f0 + r) * DMODEL + c8;
    lbB = (tid & ~63) * 16;
  }

  const f32x4 fz = {0.f, 0.f, 0.f, 0.f};
  f32x4 acc1[4][2], acc3[4][2];
#pragma unroll
  for (int m = 0; m < 4; ++m)
#pragma unroll
    for (int n = 0; n < 2; ++n) { acc1[m][n] = fz; acc3[m][n] = fz; }

#define G1_STAGE(BUF, K0)                                                     \
  do {                                                                        \
    _Pragma("unroll") for (int it = 0; it < 2; ++it)                          \
        gload_lds16(xb + aoff[it] + (K0), AS_BUF(BUF) + lbA[it]);             \
    gload_lds16(w1t + boff + (K0), B1S_BUF(BUF) + lbB);                       \
    gload_lds16(w3t + boff + (K0), B3S_BUF(BUF) + lbB);                       \
  } while (0)

#define G1_COMPUTE(BUF)                                                       \
  do {                                                                        \
    __builtin_amdgcn_s_setprio(1);                                            \
    bf16x8 af[4], b1f[2], b3f[2];                                             \
    _Pragma("unroll") for (int m = 0; m < 4; ++m)                             \
        af[m] = *(const bf16x8*)(AS_BUF(BUF) +                                \
                                 (wr * 64 + m * 16 + l15) * 64 + ko);         \
    _Pragma("unroll") for (int n = 0; n < 2; ++n) {                           \
      const int ro = (wc * 32 + n * 16 + l15) * 64 + ko;                      \
      b1f[n] = *(const bf16x8*)(B1S_BUF(BUF) + ro);                           \
      b3f[n] = *(const bf16x8*)(B3S_BUF(BUF) + ro);                           \
    }                                                                         \
    _Pragma("unroll") for (int m = 0; m < 4; ++m)                             \
        _Pragma("unroll") for (int n = 0; n < 2; ++n) {                       \
      acc1[m][n] = __builtin_amdgcn_mfma_f32_16x16x32_bf16(af[m], b1f[n],     \
                                                           acc1[m][n], 0, 0, 0); \
      acc3[m][n] = __builtin_amdgcn_mfma_f32_16x16x32_bf16(af[m], b3f[n],     \
                                                           acc3[m][n], 0, 0, 0); \
    }                                                                         \
    __builtin_amdgcn_s_setprio(0);                                            \
  } while (0)

  G1_STAGE(0, 0);
#pragma unroll
  for (int t = 0; t < 15; ++t) {
    G1_STAGE((t + 1) & 1, (t + 1) * 32);
    PIPE_BAR_4();
    G1_COMPUTE(t & 1);
    POST_BAR();
  }
  PIPE_BAR_0();
  G1_COMPUTE(1);

  __syncthreads();
  {
    __bf16* eps = (__bf16*)smem;
    constexpr int EW = 72;
#pragma unroll
    for (int m = 0; m < 4; ++m)
#pragma unroll
      for (int n = 0; n < 2; ++n)
#pragma unroll
        for (int r = 0; r < 4; ++r) {
          const int row = wr * 64 + m * 16 + lhi * 4 + r;
          const int col = wc * 32 + n * 16 + l15;
          const float g = acc1[m][n][r];
          const float u = acc3[m][n][r];
          eps[row * EW + col] = (__bf16)((g / (1.f + __expf(-g))) * u * comb[row]);
        }
    __syncthreads();
#pragma unroll
    for (int p = 0; p < 4; ++p) {
      const int i = p * 256 + tid;
      const int row = i >> 3, c8 = (i & 7) * 8;
      *(bf16x8*)&hbuf[(size_t)(m0 + row) * FFN + f0 + c8] =
          *(const bf16x8*)&eps[row * EW + c8];
    }
  }
#undef G1_STAGE
#undef G1_COMPUTE
#undef AS_BUF
#undef B1S_BUF
#undef B3S_BUF
}

// ---------------- k4: GEMM2 sparse: 128x64, BK=32, split-K=2, counted-vmcnt ----------------
__global__ __launch_bounds__(256) void gemm2_kernel(
    const __bf16* __restrict__ hbuf, const __bf16* __restrict__ w2t,
    const int* __restrict__ sched_e, __bf16* __restrict__ outp) {
  __shared__ alignas(16) char smem[24576];
#define AS_BUF(b) (smem + (b)*8192)
#define BS_BUF(b) (smem + 16384 + (b)*4096)
  const int tid = threadIdx.x;
  const int id = blockIdx.x;
  const int gk = (id & 7) + ((id >> 6) << 3);
  const int n0 = ((id >> 3) & 7) * 64;
  const int mb = gk >> 1;
  const int kz = gk & 1;
  const int e = sched_e[mb];
  if (e < 0) return;
  const int m0 = mb * 128;
  const int fbase = kz * (FFN / 2);
  const int lane = tid & 63;
  const int wv = tid >> 6;
  const int wr = wv >> 1, wc = wv & 1;
  const int l15 = lane & 15, lhi = lane >> 4;
  const int ko = (lhi ^ ((l15 >> 1) & 3)) << 4;

  size_t aoff[2];
  int lbA[2];
#pragma unroll
  for (int it = 0; it < 2; ++it) {
    const int chunk = it * 256 + tid;
    const int r = chunk >> 2;
    const int c8 = ((chunk & 3) ^ ((r >> 1) & 3)) * 8;
    aoff[it] = (size_t)(m0 + r) * FFN + fbase + c8;
    lbA[it] = (it * 256 + (tid & ~63)) * 16;
  }
  size_t boff;
  int lbB;
  {
    const int r = tid >> 2;
    const int c8 = ((tid & 3) ^ ((r >> 1) & 3)) * 8;
    boff = ((size_t)e * DMODEL + n0 + r) * FFN + fbase + c8;
    lbB = (tid & ~63) * 16;
  }

  const f32x4 fz = {0.f, 0.f, 0.f, 0.f};
  f32x4 acc[4][2];
#pragma unroll
  for (int m = 0; m < 4; ++m) { acc[m][0] = fz; acc[m][1] = fz; }

#define G2_STAGE(BUF, K0)                                                     \
  do {                                                                        \
    _Pragma("unroll") for (int it = 0; it < 2; ++it)                          \
        gload_lds16(hbuf + aoff[it] + (K0), AS_BUF(BUF) + lbA[it]);           \
    gload_lds16(w2t + boff + (K0), BS_BUF(BUF) + lbB);                        \
  } while (0)

#define G2_COMPUTE(BUF)                                                       \
  do {                                                                        \
    __builtin_amdgcn_s_setprio(1);                                            \
    bf16x8 af[4], bfr[2];                                                     \
    _Pragma("unroll") for (int m = 0; m < 4; ++m)                             \
        af[m] = *(const bf16x8*)(AS_BUF(BUF) +                                \
                                 (wr * 64 + m * 16 + l15) * 64 + ko);         \
    _Pragma("unroll") for (int n = 0; n < 2; ++n)                             \
        bfr[n] = *(const bf16x8*)(BS_BUF(BUF) +                               \
                                  (wc * 32 + n * 16 + l15) * 64 + ko);        \
    _Pragma("unroll") for (int m = 0; m < 4; ++m)                             \
        _Pragma("unroll") for (int n = 0; n < 2; ++n)                         \
            acc[m][n] = __builtin_amdgcn_mfma_f32_16x16x32_bf16(              \
                af[m], bfr[n], acc[m][n], 0, 0, 0);                           \
    __builtin_amdgcn_s_setprio(0);                                            \
  } while (0)

  G2_STAGE(0, 0);
#pragma unroll
  for (int t = 0; t < 15; ++t) {
    G2_STAGE((t + 1) & 1, (t + 1) * 32);
    PIPE_BAR_3();
    G2_COMPUTE(t & 1);
    POST_BAR();
  }
  PIPE_BAR_0();
  G2_COMPUTE(1);

  __syncthreads();
  {
    __bf16* eps = (__bf16*)smem;
    constexpr int EW = 72;
#pragma unroll
    for (int m = 0; m < 4; ++m)
#pragma unroll
      for (int n = 0; n < 2; ++n)
#pragma unroll
        for (int r = 0; r < 4; ++r) {
          const int row = wr * 64 + m * 16 + lhi * 4 + r;
          const int col = wc * 32 + n * 16 + l15;
          eps[row * EW + col] = (__bf16)acc[m][n][r];
        }
    __syncthreads();
#pragma unroll
    for (int p = 0; p < 4; ++p) {
      const int i = p * 256 + tid;
      const int row = i >> 3, c8 = (i & 7) * 8;
      *(bf16x8*)&outp[((size_t)kz * PCAP + m0 + row) * DMODEL + n0 + c8] =
          *(const bf16x8*)&eps[row * EW + c8];
    }
  }
#undef G2_STAGE
#undef G2_COMPUTE
#undef AS_BUF
#undef BS_BUF
}

// ---------------- k5: gather: out[t] = sum of 2 pairs x 2 kz ----------------
__global__ __launch_bounds__(256) void gather_kernel(
    const __bf16* __restrict__ outp, const int* __restrict__ pairidx,
    float* __restrict__ out) {
  const int i = blockIdx.x * 256 + threadIdx.x;
  const int t = i >> 6;
  const int c = (i & 63) * 8;
  const int p0 = pairidx[t * 2];
  const int p1 = pairidx[t * 2 + 1];
  const size_t KZ = (size_t)PCAP * DMODEL;
  const bf16x8 a0 = *(const bf16x8*)&outp[(size_t)p0 * DMODEL + c];
  const bf16x8 a1 = *(const bf16x8*)&outp[(size_t)p1 * DMODEL + c];
  const bf16x8 b0 = *(const bf16x8*)&outp[KZ + (size_t)p0 * DMODEL + c];
  const bf16x8 b1 = *(const bf16x8*)&outp[KZ + (size_t)p1 * DMODEL + c];
  f32x4 lo, hi;
#pragma unroll
  for (int j = 0; j < 4; ++j)
    lo[j] = (float)a0[j] + (float)a1[j] + (float)b0[j] + (float)b1[j];
#pragma unroll
  for (int j = 0; j < 4; ++j)
    hi[j] = (float)a0[j + 4] + (float)a1[j + 4] + (float)b0[j + 4] + (float)b1[j + 4];
  float* op = out + (size_t)t * DMODEL + c;
  *(f32x4*)op = lo;
  *(f32x4*)(op + 4) = hi;
}

extern "C" void kernel_launch(void* const* d_in, const int* in_sizes, int n_in,
                              void* d_out, int out_size, void* d_ws, size_t ws_size,
                              hipStream_t stream) {
  const float* x = (const float*)d_in[0];
  const float* rw = (const float*)d_in[1];
  const float* w1 = (const float*)d_in[2];
  const float* w2 = (const float*)d_in[3];
  const float* w3 = (const float*)d_in[4];
  float* out = (float*)d_out;
  char* ws = (char*)d_ws;

  int* tope = (int*)(ws + 0);                  //    16,384
  float* topw = (float*)(ws + 16384);          //    16,384
  int* pair_t = (int*)(ws + 32768);            //    20,480
  float* pair_w = (float*)(ws + 53248);        //    20,480
  int* pairidx = (int*)(ws + 73728);           //    16,384
  int* sched_e = (int*)(ws + 90112);           //     8,192 (padded)
  __bf16* xb = (__bf16*)(ws + 98304);          // 2,097,152
  __bf16* w1t = (__bf16*)(ws + 2195456);       // 8,388,608  [E][F][D]
  __bf16* w3t = (__bf16*)(ws + 10584064);      // 8,388,608  [E][F][D]
  __bf16* w2t = (__bf16*)(ws + 18972672);      // 8,388,608  [E][D][F]
  __bf16* hbuf = (__bf16*)(ws + 27361280);     // 10,485,760 [PCAP][F]
  __bf16* outp = (__bf16*)(ws + 37847040);     // 10,485,760 [2][PCAP][D] bf16

  hipLaunchKernelGGL(router_kernel, dim3(520), dim3(256), 0, stream,
                     x, rw, xb, tope, topw, pair_t, pair_w, sched_e);
  hipLaunchKernelGGL(trans13_build_kernel, dim3(2049), dim3(256), 0, stream,
                     w1, w3, w1t, w3t, tope, topw, pair_t, pair_w, pairidx, sched_e);
  hipLaunchKernelGGL(gemm1_kernel, dim3(640 + 1024), dim3(256), 0, stream,
                     xb, w1t, w3t, w2, w2t, pair_t, pair_w, sched_e, hbuf);
  hipLaunchKernelGGL(gemm2_kernel, dim3(640), dim3(256), 0, stream,
                     hbuf, w2t, sched_e, outp);
  hipLaunchKernelGGL(gather_kernel, dim3(512), dim3(256), 0, stream,
                     outp, pairidx, out);
}